// Round 1
// baseline (518.005 us; speedup 1.0000x reference)
//
#include <hip/hip_runtime.h>
#include <hip/hip_bf16.h>
#include <math.h>

#define DPOS 768
#define ROWS 8192           // 32*256
#define NEG_INF_V (-10000.0f)
#define NSPLIT 4

typedef __attribute__((ext_vector_type(8))) __bf16 bf16x8;
typedef __attribute__((ext_vector_type(4))) __bf16 bf16x4;
typedef __attribute__((ext_vector_type(4))) float f32x4;

// ---------------- fp32 -> bf16 conversion ----------------
__global__ __launch_bounds__(256) void k_f2bf(const float* __restrict__ src,
                                              __bf16* __restrict__ dst, int n) {
    int i = (blockIdx.x * blockDim.x + threadIdx.x) * 4;
    if (i < n) {
        float4 v = *(const float4*)(src + i);
        bf16x4 o = {(__bf16)v.x, (__bf16)v.y, (__bf16)v.z, (__bf16)v.w};
        *(bf16x4*)(dst + i) = o;
    }
}

// ---------------- GEMM C = A * B^T  (+bias, epilogue) ----------------
// A: [M][768] bf16, B: [N][768] bf16 (row-major = B^T layout)
// MODE 0: out fp32 = gelu(acc + bias)   MODE 1: out bf16 = acc + bias
template <int MODE>
__global__ __launch_bounds__(256) void k_gemm_bt(const __bf16* __restrict__ A,
                                                 const __bf16* __restrict__ B,
                                                 const float* __restrict__ bias,
                                                 float* __restrict__ outF,
                                                 __bf16* __restrict__ outB) {
    const int lane = threadIdx.x & 63;
    const int wave = threadIdx.x >> 6;
    const int wr = wave >> 1, wc = wave & 1;  // 2x2 waves -> 128x64 block tile
    const int row0 = blockIdx.x * 128 + wr * 64;
    const int col0 = blockIdx.y * 64 + wc * 32;
    const int lr = lane & 15;
    const int lk = (lane >> 4) * 8;

    f32x4 acc[4][2] = {};
    for (int k0 = 0; k0 < DPOS; k0 += 32) {
        bf16x8 a[4], b[2];
#pragma unroll
        for (int f = 0; f < 4; ++f)
            a[f] = *(const bf16x8*)(A + (size_t)(row0 + f * 16 + lr) * DPOS + k0 + lk);
#pragma unroll
        for (int f = 0; f < 2; ++f)
            b[f] = *(const bf16x8*)(B + (size_t)(col0 + f * 16 + lr) * DPOS + k0 + lk);
#pragma unroll
        for (int i = 0; i < 4; ++i)
#pragma unroll
            for (int j = 0; j < 2; ++j)
                acc[i][j] = __builtin_amdgcn_mfma_f32_16x16x32_bf16(a[i], b[j], acc[i][j], 0, 0, 0);
    }
    const int rr = (lane >> 4) * 4;
#pragma unroll
    for (int i = 0; i < 4; ++i)
#pragma unroll
        for (int j = 0; j < 2; ++j) {
            int col = col0 + j * 16 + lr;
            float bv = bias[col];
#pragma unroll
            for (int v = 0; v < 4; ++v) {
                int row = row0 + i * 16 + rr + v;
                float val = acc[i][j][v] + bv;
                if (MODE == 0) {
                    val = 0.5f * val * (1.0f + erff(val * 0.70710678118654752f));
                    outF[(size_t)row * DPOS + col] = val;
                } else {
                    outB[(size_t)row * DPOS + col] = (__bf16)val;
                }
            }
        }
}

// ---------------- LayerNorm over last dim (768), one block per row ----------------
__global__ __launch_bounds__(256) void k_ln(const float* __restrict__ h,
                                            const float* __restrict__ g,
                                            const float* __restrict__ bta,
                                            __bf16* __restrict__ out) {
    int row = blockIdx.x;
    const float* hr = h + (size_t)row * DPOS;
    float v[3], s = 0.f, sq = 0.f;
#pragma unroll
    for (int t = 0; t < 3; ++t) {
        v[t] = hr[threadIdx.x + t * 256];
        s += v[t];
        sq += v[t] * v[t];
    }
#pragma unroll
    for (int m = 32; m >= 1; m >>= 1) {
        s += __shfl_xor(s, m);
        sq += __shfl_xor(sq, m);
    }
    __shared__ float ss[4], sqq[4];
    int wave = threadIdx.x >> 6, lane = threadIdx.x & 63;
    if (lane == 0) { ss[wave] = s; sqq[wave] = sq; }
    __syncthreads();
    s = ss[0] + ss[1] + ss[2] + ss[3];
    sq = sqq[0] + sqq[1] + sqq[2] + sqq[3];
    float mu = s * (1.0f / DPOS);
    float var = sq * (1.0f / DPOS) - mu * mu;
    float r = rsqrtf(var + 1e-12f);
#pragma unroll
    for (int t = 0; t < 3; ++t) {
        int c = threadIdx.x + t * 256;
        out[(size_t)row * DPOS + c] = (__bf16)((v[t] - mu) * r * g[c] + bta[c]);
    }
}

// ---------------- fused logits + row-wise online logsumexp ----------------
// grid: (ROWS/64, NSPLIT). Block 256 thr = 4 waves; per iter block covers 64 rows x 256 cols.
__global__ __launch_bounds__(256, 2) void k_lse(const __bf16* __restrict__ E,
                                                const __bf16* __restrict__ L,
                                                const float* __restrict__ vm,
                                                float* __restrict__ pm,
                                                float* __restrict__ ps) {
    const int lane = threadIdx.x & 63;
    const int wave = threadIdx.x >> 6;
    const int row0 = blockIdx.x * 64;
    const int split = blockIdx.y;
    const int lr = lane & 15;
    const int lk = (lane >> 4) * 8;
    const int rr = (lane >> 4) * 4;

    // row-mask bits for this lane's 16 (fr,v) rows
    unsigned mrow = 0;
#pragma unroll
    for (int fr = 0; fr < 4; ++fr)
#pragma unroll
        for (int v = 0; v < 4; ++v)
            if (vm[row0 + fr * 16 + rr + v] != 0.0f) mrow |= 1u << (fr * 4 + v);

    float rm[4][4], rs[4][4];
#pragma unroll
    for (int i = 0; i < 4; ++i)
#pragma unroll
        for (int v = 0; v < 4; ++v) { rm[i][v] = -1e30f; rs[i][v] = 0.f; }

    const int COLS = ROWS / NSPLIT;     // 2048
    const int ITERS = COLS / 256;       // 8

    for (int it = 0; it < ITERS; ++it) {
        const int c0 = split * COLS + it * 256 + wave * 64;
        float cm[4];
#pragma unroll
        for (int fc = 0; fc < 4; ++fc) cm[fc] = vm[c0 + fc * 16 + lr];

        f32x4 acc[4][4] = {};
        for (int k0 = 0; k0 < DPOS; k0 += 32) {
            bf16x8 a[4], b[4];
#pragma unroll
            for (int f = 0; f < 4; ++f)
                a[f] = *(const bf16x8*)(E + (size_t)(row0 + f * 16 + lr) * DPOS + k0 + lk);
#pragma unroll
            for (int f = 0; f < 4; ++f)
                b[f] = *(const bf16x8*)(L + (size_t)(c0 + f * 16 + lr) * DPOS + k0 + lk);
#pragma unroll
            for (int i = 0; i < 4; ++i)
#pragma unroll
                for (int j = 0; j < 4; ++j)
                    acc[i][j] = __builtin_amdgcn_mfma_f32_16x16x32_bf16(a[i], b[j], acc[i][j], 0, 0, 0);
        }
        // per-lane online (m,s) update over this lane's 4 columns per row
#pragma unroll
        for (int i = 0; i < 4; ++i)
#pragma unroll
            for (int v = 0; v < 4; ++v) {
                bool mi = (mrow >> (i * 4 + v)) & 1u;
                float x0 = acc[i][0][v] + ((mi && cm[0] == 0.f) ? NEG_INF_V : 0.f);
                float x1 = acc[i][1][v] + ((mi && cm[1] == 0.f) ? NEG_INF_V : 0.f);
                float x2 = acc[i][2][v] + ((mi && cm[2] == 0.f) ? NEG_INF_V : 0.f);
                float x3 = acc[i][3][v] + ((mi && cm[3] == 0.f) ? NEG_INF_V : 0.f);
                float tm = fmaxf(fmaxf(x0, x1), fmaxf(x2, x3));
                float nm = fmaxf(rm[i][v], tm);
                float sc = __expf(rm[i][v] - nm);
                rs[i][v] = rs[i][v] * sc + __expf(x0 - nm) + __expf(x1 - nm) +
                           __expf(x2 - nm) + __expf(x3 - nm);
                rm[i][v] = nm;
            }
    }
    // cross-lane merge within each 16-lane group
#pragma unroll
    for (int i = 0; i < 4; ++i)
#pragma unroll
        for (int v = 0; v < 4; ++v) {
            float m = rm[i][v], s = rs[i][v];
#pragma unroll
            for (int d = 1; d < 16; d <<= 1) {
                float mo = __shfl_xor(m, d);
                float so = __shfl_xor(s, d);
                float nm = fmaxf(m, mo);
                s = s * __expf(m - nm) + so * __expf(mo - nm);
                m = nm;
            }
            rm[i][v] = m;
            rs[i][v] = s;
        }
    // combine 4 waves via LDS
    __shared__ float lm[4][64], lsd[4][64];
    if (lr == 0) {
#pragma unroll
        for (int i = 0; i < 4; ++i)
#pragma unroll
            for (int v = 0; v < 4; ++v) {
                int r = i * 16 + rr + v;
                lm[wave][r] = rm[i][v];
                lsd[wave][r] = rs[i][v];
            }
    }
    __syncthreads();
    int t = threadIdx.x;
    if (t < 64) {
        float m = lm[0][t], s = lsd[0][t];
#pragma unroll
        for (int w = 1; w < 4; ++w) {
            float mo = lm[w][t], so = lsd[w][t];
            float nm = fmaxf(m, mo);
            s = s * __expf(m - nm) + so * __expf(mo - nm);
            m = nm;
        }
        pm[(size_t)(row0 + t) * NSPLIT + split] = m;
        ps[(size_t)(row0 + t) * NSPLIT + split] = s;
    }
}

// ---------------- diagonal: diag[i] = dot(emb_i, labels_i) ----------------
__global__ __launch_bounds__(256) void k_diag(const __bf16* __restrict__ E,
                                              const __bf16* __restrict__ L,
                                              float* __restrict__ diag) {
    int wave = threadIdx.x >> 6, lane = threadIdx.x & 63;
    int row = blockIdx.x * 4 + wave;
    const __bf16* e = E + (size_t)row * DPOS;
    const __bf16* l = L + (size_t)row * DPOS;
    float s = 0.f;
    for (int k = lane * 8; k < DPOS; k += 64 * 8) {
        bf16x8 a = *(const bf16x8*)(e + k);
        bf16x8 b = *(const bf16x8*)(l + k);
#pragma unroll
        for (int j = 0; j < 8; ++j) s += (float)a[j] * (float)b[j];
    }
#pragma unroll
    for (int m = 32; m >= 1; m >>= 1) s += __shfl_xor(s, m);
    if (lane == 0) diag[row] = s;
}

// ---------------- combine partials + masked mean ----------------
__global__ __launch_bounds__(256) void k_loss(const float* __restrict__ pm,
                                              const float* __restrict__ ps,
                                              const float* __restrict__ diag,
                                              const int* __restrict__ idx,
                                              float* __restrict__ out) {
    float accn = 0.f, accd = 0.f;
    for (int i = threadIdx.x; i < ROWS; i += 256) {
        float m = pm[i * NSPLIT + 0], s = ps[i * NSPLIT + 0];
#pragma unroll
        for (int c = 1; c < NSPLIT; ++c) {
            float mo = pm[i * NSPLIT + c], so = ps[i * NSPLIT + c];
            float nm = fmaxf(m, mo);
            s = s * __expf(m - nm) + so * __expf(mo - nm);
            m = nm;
        }
        float lse = m + logf(s);
        bool valid = (idx[i] != -100);
        if (valid) {
            accn += diag[i] - lse;
            accd += 1.f;
        }
    }
#pragma unroll
    for (int m = 32; m >= 1; m >>= 1) {
        accn += __shfl_xor(accn, m);
        accd += __shfl_xor(accd, m);
    }
    __shared__ float an[4], ad[4];
    int wave = threadIdx.x >> 6, lane = threadIdx.x & 63;
    if (lane == 0) { an[wave] = accn; ad[wave] = accd; }
    __syncthreads();
    if (threadIdx.x == 0) {
        float n = an[0] + an[1] + an[2] + an[3];
        float d = ad[0] + ad[1] + ad[2] + ad[3];
        out[0] = -n / d;
    }
}

extern "C" void kernel_launch(void* const* d_in, const int* in_sizes, int n_in,
                              void* d_out, int out_size, void* d_ws, size_t ws_size,
                              hipStream_t stream) {
    const float* x      = (const float*)d_in[0];   // [8192][768]
    const float* labels = (const float*)d_in[1];   // [8192][768]
    const int*   lidx   = (const int*)d_in[2];     // [8192]
    const float* vm     = (const float*)d_in[3];   // [8192]
    const float* W1     = (const float*)d_in[4];   // [768][768]
    const float* b1     = (const float*)d_in[5];
    const float* ln_g   = (const float*)d_in[6];
    const float* ln_b   = (const float*)d_in[7];
    const float* Wd     = (const float*)d_in[8];
    const float* b_dec  = (const float*)d_in[9];
    float* out = (float*)d_out;

    const size_t NE = (size_t)ROWS * DPOS;       // 6291456
    const size_t NW = (size_t)DPOS * DPOS;       // 589824
    char* p = (char*)d_ws;
    __bf16* xb   = (__bf16*)p;            p += NE * 2;
    __bf16* labb = (__bf16*)p;            p += NE * 2;
    __bf16* W1b  = (__bf16*)p;            p += NW * 2;
    __bf16* Wdb  = (__bf16*)p;            p += NW * 2;
    float*  h    = (float*)p;             p += NE * 4;
    __bf16* hlnb = (__bf16*)p;            p += NE * 2;
    __bf16* embb = (__bf16*)p;            p += NE * 2;
    float*  pm   = (float*)p;             p += (size_t)ROWS * NSPLIT * 4;
    float*  ps   = (float*)p;             p += (size_t)ROWS * NSPLIT * 4;
    float*  diag = (float*)p;             p += (size_t)ROWS * 4;

    // convert fp32 -> bf16
    k_f2bf<<<(NE / 4 + 255) / 256, 256, 0, stream>>>(x, xb, (int)NE);
    k_f2bf<<<(NE / 4 + 255) / 256, 256, 0, stream>>>(labels, labb, (int)NE);
    k_f2bf<<<(NW / 4 + 255) / 256, 256, 0, stream>>>(W1, W1b, (int)NW);
    k_f2bf<<<(NW / 4 + 255) / 256, 256, 0, stream>>>(Wd, Wdb, (int)NW);

    // MFM block
    dim3 g1(ROWS / 128, DPOS / 64);
    k_gemm_bt<0><<<g1, 256, 0, stream>>>(xb, W1b, b1, h, nullptr);
    k_ln<<<ROWS, 256, 0, stream>>>(h, ln_g, ln_b, hlnb);
    k_gemm_bt<1><<<g1, 256, 0, stream>>>(hlnb, Wdb, b_dec, nullptr, embb);

    // contrastive loss
    dim3 g2(ROWS / 64, NSPLIT);
    k_lse<<<g2, 256, 0, stream>>>(embb, labb, vm, pm, ps);
    k_diag<<<ROWS / 4, 256, 0, stream>>>(embb, labb, diag);
    k_loss<<<1, 256, 0, stream>>>(pm, ps, diag, lidx, out);
}

// Round 2
// 315.721 us; speedup vs baseline: 1.6407x; 1.6407x over previous
//
#include <hip/hip_runtime.h>
#include <hip/hip_bf16.h>
#include <math.h>

#define DPOS 768
#define ROWS 8192           // 32*256
#define NEG_INF_V (-10000.0f)
#define NSPLIT 8

#define BM 128
#define BN 128
#define BK 64
#define CPS (ROWS / NSPLIT)   // cols per split = 1024
#define NCT (CPS / BN)        // col-tiles per block = 8
#define NKC (DPOS / BK)       // k-chunks = 12

typedef __attribute__((ext_vector_type(8))) __bf16 bf16x8;
typedef __attribute__((ext_vector_type(4))) __bf16 bf16x4;
typedef __attribute__((ext_vector_type(4))) float f32x4;

typedef const __attribute__((address_space(1))) unsigned int* gptr_t;
typedef __attribute__((address_space(3))) unsigned int* lptr_t;

// ---------------- fp32 -> bf16 conversion ----------------
__global__ __launch_bounds__(256) void k_f2bf(const float* __restrict__ src,
                                              __bf16* __restrict__ dst, int n) {
    int i = (blockIdx.x * blockDim.x + threadIdx.x) * 4;
    if (i < n) {
        float4 v = *(const float4*)(src + i);
        bf16x4 o = {(__bf16)v.x, (__bf16)v.y, (__bf16)v.z, (__bf16)v.w};
        *(bf16x4*)(dst + i) = o;
    }
}

// ---------------- GEMM C = A * B^T  (+bias, epilogue) ----------------
template <int MODE>
__global__ __launch_bounds__(256) void k_gemm_bt(const __bf16* __restrict__ A,
                                                 const __bf16* __restrict__ B,
                                                 const float* __restrict__ bias,
                                                 float* __restrict__ outF,
                                                 __bf16* __restrict__ outB) {
    const int lane = threadIdx.x & 63;
    const int wave = threadIdx.x >> 6;
    const int wr = wave >> 1, wc = wave & 1;  // 2x2 waves -> 128x64 block tile
    const int row0 = blockIdx.x * 128 + wr * 64;
    const int col0 = blockIdx.y * 64 + wc * 32;
    const int lr = lane & 15;
    const int lk = (lane >> 4) * 8;

    f32x4 acc[4][2] = {};
    for (int k0 = 0; k0 < DPOS; k0 += 32) {
        bf16x8 a[4], b[2];
#pragma unroll
        for (int f = 0; f < 4; ++f)
            a[f] = *(const bf16x8*)(A + (size_t)(row0 + f * 16 + lr) * DPOS + k0 + lk);
#pragma unroll
        for (int f = 0; f < 2; ++f)
            b[f] = *(const bf16x8*)(B + (size_t)(col0 + f * 16 + lr) * DPOS + k0 + lk);
#pragma unroll
        for (int i = 0; i < 4; ++i)
#pragma unroll
            for (int j = 0; j < 2; ++j)
                acc[i][j] = __builtin_amdgcn_mfma_f32_16x16x32_bf16(a[i], b[j], acc[i][j], 0, 0, 0);
    }
    const int rr = (lane >> 4) * 4;
#pragma unroll
    for (int i = 0; i < 4; ++i)
#pragma unroll
        for (int j = 0; j < 2; ++j) {
            int col = col0 + j * 16 + lr;
            float bv = bias[col];
#pragma unroll
            for (int v = 0; v < 4; ++v) {
                int row = row0 + i * 16 + rr + v;
                float val = acc[i][j][v] + bv;
                if (MODE == 0) {
                    val = 0.5f * val * (1.0f + erff(val * 0.70710678118654752f));
                    outF[(size_t)row * DPOS + col] = val;
                } else {
                    outB[(size_t)row * DPOS + col] = (__bf16)val;
                }
            }
        }
}

// ---------------- LayerNorm over last dim (768), one block per row ----------------
__global__ __launch_bounds__(256) void k_ln(const float* __restrict__ h,
                                            const float* __restrict__ g,
                                            const float* __restrict__ bta,
                                            __bf16* __restrict__ out) {
    int row = blockIdx.x;
    const float* hr = h + (size_t)row * DPOS;
    float v[3], s = 0.f, sq = 0.f;
#pragma unroll
    for (int t = 0; t < 3; ++t) {
        v[t] = hr[threadIdx.x + t * 256];
        s += v[t];
        sq += v[t] * v[t];
    }
#pragma unroll
    for (int m = 32; m >= 1; m >>= 1) {
        s += __shfl_xor(s, m);
        sq += __shfl_xor(sq, m);
    }
    __shared__ float ss[4], sqq[4];
    int wave = threadIdx.x >> 6, lane = threadIdx.x & 63;
    if (lane == 0) { ss[wave] = s; sqq[wave] = sq; }
    __syncthreads();
    s = ss[0] + ss[1] + ss[2] + ss[3];
    sq = sqq[0] + sqq[1] + sqq[2] + sqq[3];
    float mu = s * (1.0f / DPOS);
    float var = sq * (1.0f / DPOS) - mu * mu;
    float r = rsqrtf(var + 1e-12f);
#pragma unroll
    for (int t = 0; t < 3; ++t) {
        int c = threadIdx.x + t * 256;
        out[(size_t)row * DPOS + c] = (__bf16)((v[t] - mu) * r * g[c] + bta[c]);
    }
}

// ---------------- fused logits + row-wise online logsumexp ----------------
// m97-style: 128x128 tile, BK=64, LDS double-buffer via global_load_lds(16B),
// XOR-swizzled layout (pre-swizzled global source, swizzled ds_read).
// grid: (ROWS/BM, NSPLIT); block 256 = 4 waves (2x2), 64x64 out per wave.
__global__ __launch_bounds__(256, 2) void k_lse(const __bf16* __restrict__ E,
                                                const __bf16* __restrict__ L,
                                                const float* __restrict__ vm,
                                                float* __restrict__ pm,
                                                float* __restrict__ ps) {
    __shared__ __bf16 lds[2][2][BM * BK];   // [buf][A=0/B=1][...]  64 KB

    const int lane = threadIdx.x & 63;
    const int wave = threadIdx.x >> 6;
    const int wr = wave >> 1, wc = wave & 1;
    const int row0 = blockIdx.x * BM;
    const int split = blockIdx.y;
    const int lr = lane & 15;
    const int lk = (lane >> 4) * 8;
    const int rr = (lane >> 4) * 4;

    // row-mask bits for this lane's 16 rows (wr half of the 128-row tile)
    unsigned mrow = 0;
#pragma unroll
    for (int i = 0; i < 4; ++i)
#pragma unroll
        for (int v = 0; v < 4; ++v)
            if (vm[row0 + wr * 64 + i * 16 + rr + v] != 0.0f) mrow |= 1u << (i * 4 + v);

    // precompute staging geometry (invariant across tiles / k-chunks)
    int soff[4], srow[4], ssrc[4];
#pragma unroll
    for (int c = 0; c < 4; ++c) {
        int off = wave * 4096 + c * 1024 + lane * 16;   // byte offset in 16KB buffer
        soff[c] = off;
        srow[c] = off >> 7;                             // row in [0,128)
        ssrc[c] = (off & 127) ^ ((srow[c] & 7) << 4);   // pre-swizzled source col-byte
    }

    auto stage = [&](int buf, int kc, int ct0) {
        const char* Ab = (const char*)E + (size_t)row0 * (DPOS * 2) + kc * (BK * 2);
        const char* Bb = (const char*)L + (size_t)ct0 * (DPOS * 2) + kc * (BK * 2);
        char* lA = (char*)&lds[buf][0][0];
        char* lB = (char*)&lds[buf][1][0];
#pragma unroll
        for (int c = 0; c < 4; ++c) {
            __builtin_amdgcn_global_load_lds(
                (gptr_t)(Ab + (size_t)srow[c] * (DPOS * 2) + ssrc[c]),
                (lptr_t)(lA + soff[c]), 16, 0, 0);
            __builtin_amdgcn_global_load_lds(
                (gptr_t)(Bb + (size_t)srow[c] * (DPOS * 2) + ssrc[c]),
                (lptr_t)(lB + soff[c]), 16, 0, 0);
        }
    };

    auto rdA = [&](int buf, int i, int kk) -> bf16x8 {
        int r = wr * 64 + i * 16 + lr;
        int byte = (r * 128 + (kk + lk) * 2) ^ ((r & 7) << 4);
        return *(const bf16x8*)((const char*)&lds[buf][0][0] + byte);
    };
    auto rdB = [&](int buf, int j, int kk) -> bf16x8 {
        int r = wc * 64 + j * 16 + lr;
        int byte = (r * 128 + (kk + lk) * 2) ^ ((r & 7) << 4);
        return *(const bf16x8*)((const char*)&lds[buf][1][0] + byte);
    };

    float rm[16], rs[16];
#pragma unroll
    for (int t = 0; t < 16; ++t) { rm[t] = -1e30f; rs[t] = 0.f; }

    for (int ct = 0; ct < NCT; ++ct) {
        const int ct0 = split * CPS + ct * BN;
        // column masks for this wave's 64 cols (4 per lane)
        float cm[4];
#pragma unroll
        for (int j = 0; j < 4; ++j) cm[j] = vm[ct0 + wc * 64 + j * 16 + lr];

        f32x4 acc[4][4] = {};
        stage(0, 0, ct0);
        for (int kc = 0; kc < NKC; ++kc) {
            const int cur = kc & 1;
            if (kc + 1 < NKC) stage(cur ^ 1, kc + 1, ct0);
            __syncthreads();
#pragma unroll
            for (int kk = 0; kk < BK; kk += 32) {
                bf16x8 a[4], b[4];
#pragma unroll
                for (int i = 0; i < 4; ++i) a[i] = rdA(cur, i, kk);
#pragma unroll
                for (int j = 0; j < 4; ++j) b[j] = rdB(cur, j, kk);
#pragma unroll
                for (int i = 0; i < 4; ++i)
#pragma unroll
                    for (int j = 0; j < 4; ++j)
                        acc[i][j] = __builtin_amdgcn_mfma_f32_16x16x32_bf16(a[i], b[j], acc[i][j], 0, 0, 0);
            }
            __syncthreads();
        }

        // online (m,s) update: 16 rows x (4 cols per lane)
#pragma unroll
        for (int i = 0; i < 4; ++i)
#pragma unroll
            for (int v = 0; v < 4; ++v) {
                const int ri = i * 4 + v;
                const bool mi = (mrow >> ri) & 1u;
                float x0 = acc[i][0][v] + ((mi && cm[0] == 0.f) ? NEG_INF_V : 0.f);
                float x1 = acc[i][1][v] + ((mi && cm[1] == 0.f) ? NEG_INF_V : 0.f);
                float x2 = acc[i][2][v] + ((mi && cm[2] == 0.f) ? NEG_INF_V : 0.f);
                float x3 = acc[i][3][v] + ((mi && cm[3] == 0.f) ? NEG_INF_V : 0.f);
                float tm = fmaxf(fmaxf(x0, x1), fmaxf(x2, x3));
                float nm = fmaxf(rm[ri], tm);
                float sc = __expf(rm[ri] - nm);
                rs[ri] = rs[ri] * sc + __expf(x0 - nm) + __expf(x1 - nm) +
                         __expf(x2 - nm) + __expf(x3 - nm);
                rm[ri] = nm;
            }
    }

    // cross-lane merge within each 16-lane group (same rows, different cols)
#pragma unroll
    for (int i = 0; i < 4; ++i)
#pragma unroll
        for (int v = 0; v < 4; ++v) {
            const int ri = i * 4 + v;
            float m = rm[ri], s = rs[ri];
#pragma unroll
            for (int d = 1; d < 16; d <<= 1) {
                float mo = __shfl_xor(m, d);
                float so = __shfl_xor(s, d);
                float nm = fmaxf(m, mo);
                s = s * __expf(m - nm) + so * __expf(mo - nm);
                m = nm;
            }
            rm[ri] = m;
            rs[ri] = s;
        }

    // merge the two column-half waves via LDS (reuse staging buffer)
    float* lm = (float*)&lds[0][0][0];      // [2][128]
    float* lsd = lm + 256;                  // [2][128]
    __syncthreads();   // staging LDS no longer needed
    if (lr == 0) {
#pragma unroll
        for (int i = 0; i < 4; ++i)
#pragma unroll
            for (int v = 0; v < 4; ++v) {
                int rl = wr * 64 + i * 16 + rr + v;
                lm[wc * 128 + rl] = rm[i * 4 + v];
                lsd[wc * 128 + rl] = rs[i * 4 + v];
            }
    }
    __syncthreads();
    if (threadIdx.x < 128) {
        int t = threadIdx.x;
        float m0 = lm[t], s0 = lsd[t], m1 = lm[128 + t], s1 = lsd[128 + t];
        float nm = fmaxf(m0, m1);
        float s = s0 * __expf(m0 - nm) + s1 * __expf(m1 - nm);
        pm[(size_t)(row0 + t) * NSPLIT + split] = nm;
        ps[(size_t)(row0 + t) * NSPLIT + split] = s;
    }
}

// ---------------- diagonal: diag[i] = dot(emb_i, labels_i) ----------------
__global__ __launch_bounds__(256) void k_diag(const __bf16* __restrict__ E,
                                              const __bf16* __restrict__ L,
                                              float* __restrict__ diag) {
    int wave = threadIdx.x >> 6, lane = threadIdx.x & 63;
    int row = blockIdx.x * 4 + wave;
    const __bf16* e = E + (size_t)row * DPOS;
    const __bf16* l = L + (size_t)row * DPOS;
    float s = 0.f;
    for (int k = lane * 8; k < DPOS; k += 64 * 8) {
        bf16x8 a = *(const bf16x8*)(e + k);
        bf16x8 b = *(const bf16x8*)(l + k);
#pragma unroll
        for (int j = 0; j < 8; ++j) s += (float)a[j] * (float)b[j];
    }
#pragma unroll
    for (int m = 32; m >= 1; m >>= 1) s += __shfl_xor(s, m);
    if (lane == 0) diag[row] = s;
}

// ---------------- combine partials + masked mean ----------------
__global__ __launch_bounds__(256) void k_loss(const float* __restrict__ pm,
                                              const float* __restrict__ ps,
                                              const float* __restrict__ diag,
                                              const int* __restrict__ idx,
                                              float* __restrict__ out) {
    float accn = 0.f, accd = 0.f;
    for (int i = threadIdx.x; i < ROWS; i += 256) {
        float m = pm[i * NSPLIT + 0], s = ps[i * NSPLIT + 0];
#pragma unroll
        for (int c = 1; c < NSPLIT; ++c) {
            float mo = pm[i * NSPLIT + c], so = ps[i * NSPLIT + c];
            float nm = fmaxf(m, mo);
            s = s * __expf(m - nm) + so * __expf(mo - nm);
            m = nm;
        }
        float lse = m + logf(s);
        bool valid = (idx[i] != -100);
        if (valid) {
            accn += diag[i] - lse;
            accd += 1.f;
        }
    }
#pragma unroll
    for (int m = 32; m >= 1; m >>= 1) {
        accn += __shfl_xor(accn, m);
        accd += __shfl_xor(accd, m);
    }
    __shared__ float an[4], ad[4];
    int wave = threadIdx.x >> 6, lane = threadIdx.x & 63;
    if (lane == 0) { an[wave] = accn; ad[wave] = accd; }
    __syncthreads();
    if (threadIdx.x == 0) {
        float n = an[0] + an[1] + an[2] + an[3];
        float d = ad[0] + ad[1] + ad[2] + ad[3];
        out[0] = -n / d;
    }
}

extern "C" void kernel_launch(void* const* d_in, const int* in_sizes, int n_in,
                              void* d_out, int out_size, void* d_ws, size_t ws_size,
                              hipStream_t stream) {
    const float* x      = (const float*)d_in[0];   // [8192][768]
    const float* labels = (const float*)d_in[1];   // [8192][768]
    const int*   lidx   = (const int*)d_in[2];     // [8192]
    const float* vm     = (const float*)d_in[3];   // [8192]
    const float* W1     = (const float*)d_in[4];   // [768][768]
    const float* b1     = (const float*)d_in[5];
    const float* ln_g   = (const float*)d_in[6];
    const float* ln_b   = (const float*)d_in[7];
    const float* Wd     = (const float*)d_in[8];
    const float* b_dec  = (const float*)d_in[9];
    float* out = (float*)d_out;

    const size_t NE = (size_t)ROWS * DPOS;       // 6291456
    const size_t NW = (size_t)DPOS * DPOS;       // 589824
    char* p = (char*)d_ws;
    __bf16* xb   = (__bf16*)p;            p += NE * 2;
    __bf16* labb = (__bf16*)p;            p += NE * 2;
    __bf16* W1b  = (__bf16*)p;            p += NW * 2;
    __bf16* Wdb  = (__bf16*)p;            p += NW * 2;
    float*  h    = (float*)p;             p += NE * 4;
    __bf16* hlnb = (__bf16*)p;            p += NE * 2;
    __bf16* embb = (__bf16*)p;            p += NE * 2;
    float*  pm   = (float*)p;             p += (size_t)ROWS * NSPLIT * 4;
    float*  ps   = (float*)p;             p += (size_t)ROWS * NSPLIT * 4;
    float*  diag = (float*)p;             p += (size_t)ROWS * 4;

    // convert fp32 -> bf16
    k_f2bf<<<(NE / 4 + 255) / 256, 256, 0, stream>>>(x, xb, (int)NE);
    k_f2bf<<<(NE / 4 + 255) / 256, 256, 0, stream>>>(labels, labb, (int)NE);
    k_f2bf<<<(NW / 4 + 255) / 256, 256, 0, stream>>>(W1, W1b, (int)NW);
    k_f2bf<<<(NW / 4 + 255) / 256, 256, 0, stream>>>(Wd, Wdb, (int)NW);

    // MFM block
    dim3 g1(ROWS / 128, DPOS / 64);
    k_gemm_bt<0><<<g1, 256, 0, stream>>>(xb, W1b, b1, h, nullptr);
    k_ln<<<ROWS, 256, 0, stream>>>(h, ln_g, ln_b, hlnb);
    k_gemm_bt<1><<<g1, 256, 0, stream>>>(hlnb, Wdb, b_dec, nullptr, embb);

    // contrastive loss
    dim3 g2(ROWS / BM, NSPLIT);
    k_lse<<<g2, 256, 0, stream>>>(embb, labb, vm, pm, ps);
    k_diag<<<ROWS / 4, 256, 0, stream>>>(embb, labb, diag);
    k_loss<<<1, 256, 0, stream>>>(pm, ps, diag, lidx, out);
}

// Round 3
// 293.871 us; speedup vs baseline: 1.7627x; 1.0744x over previous
//
#include <hip/hip_runtime.h>
#include <hip/hip_bf16.h>
#include <math.h>

#define DPOS 768
#define ROWS 8192           // 32*256
#define NEG_INF_V (-10000.0f)
#define NSPLIT 8

// ---- 8-phase 256^2 geometry for k_lse8 ----
#define BM 256
#define BN 256
#define BK 64
#define CPS (ROWS / NSPLIT)   // cols per split = 1024
#define NCT (CPS / BN)        // col-tiles per block = 4
#define NKT (DPOS / BK)       // K-tiles per col-tile = 12
#define GTOT (NCT * NKT)      // 48
#define TITER (GTOT / 2)      // 24 iterations (2 K-tiles each)

typedef __attribute__((ext_vector_type(8))) __bf16 bf16x8;
typedef __attribute__((ext_vector_type(4))) __bf16 bf16x4;
typedef __attribute__((ext_vector_type(4))) float f32x4;

typedef const __attribute__((address_space(1))) unsigned int* gptr_t;
typedef __attribute__((address_space(3))) unsigned int* lptr_t;

#define SBAR() do { __builtin_amdgcn_sched_barrier(0); __builtin_amdgcn_s_barrier(); __builtin_amdgcn_sched_barrier(0); } while (0)
#define VMW(N) do { __builtin_amdgcn_sched_barrier(0); asm volatile("s_waitcnt vmcnt(" #N ")"); __builtin_amdgcn_sched_barrier(0); } while (0)

// ---------------- fp32 -> bf16 conversion ----------------
__global__ __launch_bounds__(256) void k_f2bf(const float* __restrict__ src,
                                              __bf16* __restrict__ dst, int n) {
    int i = (blockIdx.x * blockDim.x + threadIdx.x) * 4;
    if (i < n) {
        float4 v = *(const float4*)(src + i);
        bf16x4 o = {(__bf16)v.x, (__bf16)v.y, (__bf16)v.z, (__bf16)v.w};
        *(bf16x4*)(dst + i) = o;
    }
}

// ---------------- GEMM C = A * B^T  (+bias, epilogue) ----------------
template <int MODE>
__global__ __launch_bounds__(256) void k_gemm_bt(const __bf16* __restrict__ A,
                                                 const __bf16* __restrict__ B,
                                                 const float* __restrict__ bias,
                                                 float* __restrict__ outF,
                                                 __bf16* __restrict__ outB) {
    const int lane = threadIdx.x & 63;
    const int wave = threadIdx.x >> 6;
    const int wr = wave >> 1, wc = wave & 1;  // 2x2 waves -> 128x64 block tile
    const int row0 = blockIdx.x * 128 + wr * 64;
    const int col0 = blockIdx.y * 64 + wc * 32;
    const int lr = lane & 15;
    const int lk = (lane >> 4) * 8;

    f32x4 acc[4][2] = {};
    for (int k0 = 0; k0 < DPOS; k0 += 32) {
        bf16x8 a[4], b[2];
#pragma unroll
        for (int f = 0; f < 4; ++f)
            a[f] = *(const bf16x8*)(A + (size_t)(row0 + f * 16 + lr) * DPOS + k0 + lk);
#pragma unroll
        for (int f = 0; f < 2; ++f)
            b[f] = *(const bf16x8*)(B + (size_t)(col0 + f * 16 + lr) * DPOS + k0 + lk);
#pragma unroll
        for (int i = 0; i < 4; ++i)
#pragma unroll
            for (int j = 0; j < 2; ++j)
                acc[i][j] = __builtin_amdgcn_mfma_f32_16x16x32_bf16(a[i], b[j], acc[i][j], 0, 0, 0);
    }
    const int rr = (lane >> 4) * 4;
#pragma unroll
    for (int i = 0; i < 4; ++i)
#pragma unroll
        for (int j = 0; j < 2; ++j) {
            int col = col0 + j * 16 + lr;
            float bv = bias[col];
#pragma unroll
            for (int v = 0; v < 4; ++v) {
                int row = row0 + i * 16 + rr + v;
                float val = acc[i][j][v] + bv;
                if (MODE == 0) {
                    val = 0.5f * val * (1.0f + erff(val * 0.70710678118654752f));
                    outF[(size_t)row * DPOS + col] = val;
                } else {
                    outB[(size_t)row * DPOS + col] = (__bf16)val;
                }
            }
        }
}

// ---------------- LayerNorm over last dim (768), one block per row ----------------
__global__ __launch_bounds__(256) void k_ln(const float* __restrict__ h,
                                            const float* __restrict__ g,
                                            const float* __restrict__ bta,
                                            __bf16* __restrict__ out) {
    int row = blockIdx.x;
    const float* hr = h + (size_t)row * DPOS;
    float v[3], s = 0.f, sq = 0.f;
#pragma unroll
    for (int t = 0; t < 3; ++t) {
        v[t] = hr[threadIdx.x + t * 256];
        s += v[t];
        sq += v[t] * v[t];
    }
#pragma unroll
    for (int m = 32; m >= 1; m >>= 1) {
        s += __shfl_xor(s, m);
        sq += __shfl_xor(sq, m);
    }
    __shared__ float ss[4], sqq[4];
    int wave = threadIdx.x >> 6, lane = threadIdx.x & 63;
    if (lane == 0) { ss[wave] = s; sqq[wave] = sq; }
    __syncthreads();
    s = ss[0] + ss[1] + ss[2] + ss[3];
    sq = sqq[0] + sqq[1] + sqq[2] + sqq[3];
    float mu = s * (1.0f / DPOS);
    float var = sq * (1.0f / DPOS) - mu * mu;
    float r = rsqrtf(var + 1e-12f);
#pragma unroll
    for (int t = 0; t < 3; ++t) {
        int c = threadIdx.x + t * 256;
        out[(size_t)row * DPOS + c] = (__bf16)((v[t] - mu) * r * g[c] + bta[c]);
    }
}

// ---------------- fused logits + row-wise logsumexp, 8-phase 256^2 schedule ----------------
// grid (ROWS/256, NSPLIT), 512 threads = 8 waves (2M x 4N), per-wave C = 128x64.
// LDS (dynamic 128 KB): slot s at s*65536: A[256][64] at +0 (lo rows 0-127, hi 128-255),
// B[256][64] at +32768. XOR-swizzle byte ^= ((row&7)<<4); linear dest + pre-swizzled
// global source for global_load_lds, swizzled ds_read (validated round 2: 0 conflicts).
__global__ __launch_bounds__(512, 1) void k_lse8(const __bf16* __restrict__ E,
                                                 const __bf16* __restrict__ L,
                                                 const float* __restrict__ vm,
                                                 float* __restrict__ pm,
                                                 float* __restrict__ ps) {
    extern __shared__ char lds[];
    __shared__ float smm[2][4][128], sms[2][4][128];

    const int tid = threadIdx.x;
    const int lane = tid & 63;
    const int wave = tid >> 6;
    const int wr = wave >> 2, wc = wave & 3;
    const int lr = lane & 15;
    const int lk = (lane >> 4) * 8;     // k-element offset of this lane's fragment
    const int rr = (lane >> 4) * 4;
    const int row0 = blockIdx.x * BM;
    const int split = blockIdx.y;

    // ---- row-mask bits: 32 rows per lane (mi 0..7, v 0..3) ----
    unsigned mrow = 0;
#pragma unroll
    for (int mi = 0; mi < 8; ++mi) {
        float4 mv = *(const float4*)(vm + row0 + wr * 128 + mi * 16 + rr);
        if (mv.x != 0.f) mrow |= 1u << (mi * 4 + 0);
        if (mv.y != 0.f) mrow |= 1u << (mi * 4 + 1);
        if (mv.z != 0.f) mrow |= 1u << (mi * 4 + 2);
        if (mv.w != 0.f) mrow |= 1u << (mi * 4 + 3);
    }

    // ---- staging geometry: each half-tile (128 rows x 64 K) = 2 x 16B per thread ----
    const int o0 = tid * 16, o1 = o0 + 8192;          // offsets within a 16 KB region
    const int r0s = o0 >> 7, r1s = o1 >> 7;           // row within region (0..127)
    const int c0s = (o0 & 127) ^ ((r0s & 7) << 4);    // pre-swizzled source col-byte
    const int c1s = (o1 & 127) ^ ((r1s & 7) << 4);

    const char* Eb = (const char*)E + (size_t)row0 * (DPOS * 2);
    const char* Lb = (const char*)L;

    auto stageA = [&](int slot, int half, int g) {
        char* dst = lds + slot * 65536 + half * 16384;
        const char* src = Eb + (size_t)(half * 128) * (DPOS * 2) + (size_t)(g % NKT) * 128;
        __builtin_amdgcn_global_load_lds((gptr_t)(src + (size_t)r0s * (DPOS * 2) + c0s),
                                         (lptr_t)(dst + o0), 16, 0, 0);
        __builtin_amdgcn_global_load_lds((gptr_t)(src + (size_t)r1s * (DPOS * 2) + c1s),
                                         (lptr_t)(dst + o1), 16, 0, 0);
    };
    auto stageB = [&](int slot, int half, int g) {
        char* dst = lds + slot * 65536 + 32768 + half * 16384;
        const char* src = Lb + (size_t)(split * CPS + (g / NKT) * BN + half * 128) * (DPOS * 2)
                             + (size_t)(g % NKT) * 128;
        __builtin_amdgcn_global_load_lds((gptr_t)(src + (size_t)r0s * (DPOS * 2) + c0s),
                                         (lptr_t)(dst + o0), 16, 0, 0);
        __builtin_amdgcn_global_load_lds((gptr_t)(src + (size_t)r1s * (DPOS * 2) + c1s),
                                         (lptr_t)(dst + o1), 16, 0, 0);
    };

    bf16x8 a[4][2], bLo[2][2], bHi[2][2];
    f32x4 acc[8][4];
#pragma unroll
    for (int mi = 0; mi < 8; ++mi)
#pragma unroll
        for (int ni = 0; ni < 4; ++ni) acc[mi][ni] = (f32x4){0.f, 0.f, 0.f, 0.f};

    auto readA = [&](int slot, int mh) {
#pragma unroll
        for (int mi = 0; mi < 4; ++mi) {
            int r = wr * 128 + mh * 64 + mi * 16 + lr;
            int base = slot * 65536 + r * 128;
            int sw = (r & 7) << 4;
            a[mi][0] = *(const bf16x8*)(lds + base + ((lk * 2) ^ sw));
            a[mi][1] = *(const bf16x8*)(lds + base + (((32 + lk) * 2) ^ sw));
        }
    };
    auto readB = [&](int slot, int nh, bf16x8 (&dst)[2][2]) {
#pragma unroll
        for (int ni = 0; ni < 2; ++ni) {
            int r = wc * 64 + nh * 32 + ni * 16 + lr;
            int base = slot * 65536 + 32768 + r * 128;
            int sw = (r & 7) << 4;
            dst[ni][0] = *(const bf16x8*)(lds + base + ((lk * 2) ^ sw));
            dst[ni][1] = *(const bf16x8*)(lds + base + (((32 + lk) * 2) ^ sw));
        }
    };

#define MFMAQ(MI0, NI0, B) do { \
    __builtin_amdgcn_s_setprio(1); \
    _Pragma("unroll") \
    for (int mi = 0; mi < 4; ++mi) \
        _Pragma("unroll") \
        for (int ni = 0; ni < 2; ++ni) \
            _Pragma("unroll") \
            for (int kk = 0; kk < 2; ++kk) \
                acc[MI0 + mi][NI0 + ni] = __builtin_amdgcn_mfma_f32_16x16x32_bf16( \
                    a[mi][kk], B[ni][kk], acc[MI0 + mi][NI0 + ni], 0, 0, 0); \
    __builtin_amdgcn_s_setprio(0); \
} while (0)

    // running (m,s) across col-tiles, owned by threads tid<256 (one per block row)
    float Mrun = -1e30f, Srun = 0.f;

    // ---- prologue: slot0 A+B (g=0), slot1 B (g=1); slot1 A staged in iter0 ph1/ph2 ----
    stageA(0, 0, 0); stageA(0, 1, 0); stageB(0, 0, 0); stageB(0, 1, 0);
    stageB(1, 0, 1); stageB(1, 1, 1);
    VMW(4);
    SBAR();

#pragma unroll 1
    for (int i = 0; i < TITER; ++i) {
        const int g0 = 2 * i, g1 = 2 * i + 1;
        const bool tail = (i == TITER - 1);

        // ph1: read slot0 A-mh0 + B-nh0; stage slot1 A-lo (g1)
        readA(0, 0); readB(0, 0, bLo);
        stageA(1, 0, g1);
        SBAR(); MFMAQ(0, 0, bLo); SBAR();
        // ph2: read slot0 B-nh1; stage slot1 A-hi (g1)
        readB(0, 1, bHi);
        stageA(1, 1, g1);
        SBAR(); MFMAQ(0, 2, bHi); SBAR();
        // ph3: read slot0 A-mh1; stage slot0 B-lo (g0+2)
        readA(0, 1);
        if (g0 + 2 < GTOT) stageB(0, 0, g0 + 2);
        SBAR(); MFMAQ(4, 0, bLo); SBAR();
        // ph4: stage slot0 B-hi (g0+2); counted vmcnt
        if (g0 + 2 < GTOT) stageB(0, 1, g0 + 2);
        if (!tail) { VMW(4); } else { VMW(0); }
        SBAR(); MFMAQ(4, 2, bHi); SBAR();
        // ph5: read slot1 A-mh0 + B-nh0; stage slot0 A-lo (g0+2)
        readA(1, 0); readB(1, 0, bLo);
        if (g0 + 2 < GTOT) stageA(0, 0, g0 + 2);
        SBAR(); MFMAQ(0, 0, bLo); SBAR();
        // ph6: read slot1 B-nh1; stage slot0 A-hi (g0+2)
        readB(1, 1, bHi);
        if (g0 + 2 < GTOT) stageA(0, 1, g0 + 2);
        SBAR(); MFMAQ(0, 2, bHi); SBAR();
        // ph7: read slot1 A-mh1; stage slot1 B-lo (g1+2)
        readA(1, 1);
        if (g1 + 2 < GTOT) stageB(1, 0, g1 + 2);
        SBAR(); MFMAQ(4, 0, bLo); SBAR();
        // ph8: stage slot1 B-hi (g1+2); counted vmcnt
        if (g1 + 2 < GTOT) stageB(1, 1, g1 + 2);
        if (!tail) { VMW(4); }
        SBAR(); MFMAQ(4, 2, bHi); SBAR();

        // ---- col-tile epilogue: fused online-softmax over this 256x256 logits tile ----
        if ((i % (NKT / 2)) == (NKT / 2 - 1)) {
            const int ct = i / (NKT / 2);
            float cmv[4];
#pragma unroll
            for (int ni = 0; ni < 4; ++ni)
                cmv[ni] = vm[split * CPS + ct * BN + wc * 64 + ni * 16 + lr];
#pragma unroll
            for (int mi = 0; mi < 8; ++mi) {
#pragma unroll
                for (int v = 0; v < 4; ++v) {
                    bool rv = (mrow >> (mi * 4 + v)) & 1u;
                    float x0 = acc[mi][0][v] + ((rv && cmv[0] == 0.f) ? NEG_INF_V : 0.f);
                    float x1 = acc[mi][1][v] + ((rv && cmv[1] == 0.f) ? NEG_INF_V : 0.f);
                    float x2 = acc[mi][2][v] + ((rv && cmv[2] == 0.f) ? NEG_INF_V : 0.f);
                    float x3 = acc[mi][3][v] + ((rv && cmv[3] == 0.f) ? NEG_INF_V : 0.f);
                    float m4 = fmaxf(fmaxf(x0, x1), fmaxf(x2, x3));
                    float s4 = __expf(x0 - m4) + __expf(x1 - m4) +
                               __expf(x2 - m4) + __expf(x3 - m4);
#pragma unroll
                    for (int d = 1; d < 16; d <<= 1) {
                        float mo = __shfl_xor(m4, d);
                        float so = __shfl_xor(s4, d);
                        float nm = fmaxf(m4, mo);
                        s4 = s4 * __expf(m4 - nm) + so * __expf(mo - nm);
                        m4 = nm;
                    }
                    if (lr == 0) {
                        smm[wr][wc][mi * 16 + rr + v] = m4;
                        sms[wr][wc][mi * 16 + rr + v] = s4;
                    }
                }
#pragma unroll
                for (int ni = 0; ni < 4; ++ni) acc[mi][ni] = (f32x4){0.f, 0.f, 0.f, 0.f};
            }
            asm volatile("s_waitcnt lgkmcnt(0)");
            SBAR();
            if (tid < 256) {
                int rl = tid & 127, wrh = tid >> 7;
                float m = smm[wrh][0][rl], s = sms[wrh][0][rl];
#pragma unroll
                for (int w = 1; w < 4; ++w) {
                    float mo = smm[wrh][w][rl], so = sms[wrh][w][rl];
                    float nm = fmaxf(m, mo);
                    s = s * __expf(m - nm) + so * __expf(mo - nm);
                    m = nm;
                }
                float nm = fmaxf(Mrun, m);
                Srun = Srun * __expf(Mrun - nm) + s * __expf(m - nm);
                Mrun = nm;
            }
            SBAR();
        }
    }
#undef MFMAQ

    if (tid < 256) {
        int rl = tid & 127, wrh = tid >> 7;
        size_t idx = (size_t)(row0 + wrh * 128 + rl) * NSPLIT + split;
        pm[idx] = Mrun;
        ps[idx] = Srun;
    }
}

// ---------------- diagonal: diag[i] = dot(emb_i, labels_i) ----------------
__global__ __launch_bounds__(256) void k_diag(const __bf16* __restrict__ E,
                                              const __bf16* __restrict__ L,
                                              float* __restrict__ diag) {
    int wave = threadIdx.x >> 6, lane = threadIdx.x & 63;
    int row = blockIdx.x * 4 + wave;
    const __bf16* e = E + (size_t)row * DPOS;
    const __bf16* l = L + (size_t)row * DPOS;
    float s = 0.f;
    for (int k = lane * 8; k < DPOS; k += 64 * 8) {
        bf16x8 a = *(const bf16x8*)(e + k);
        bf16x8 b = *(const bf16x8*)(l + k);
#pragma unroll
        for (int j = 0; j < 8; ++j) s += (float)a[j] * (float)b[j];
    }
#pragma unroll
    for (int m = 32; m >= 1; m >>= 1) s += __shfl_xor(s, m);
    if (lane == 0) diag[row] = s;
}

// ---------------- combine partials + masked mean ----------------
__global__ __launch_bounds__(256) void k_loss(const float* __restrict__ pm,
                                              const float* __restrict__ ps,
                                              const float* __restrict__ diag,
                                              const int* __restrict__ idx,
                                              float* __restrict__ out) {
    float accn = 0.f, accd = 0.f;
    for (int i = threadIdx.x; i < ROWS; i += 256) {
        float m = pm[i * NSPLIT + 0], s = ps[i * NSPLIT + 0];
#pragma unroll
        for (int c = 1; c < NSPLIT; ++c) {
            float mo = pm[i * NSPLIT + c], so = ps[i * NSPLIT + c];
            float nm = fmaxf(m, mo);
            s = s * __expf(m - nm) + so * __expf(mo - nm);
            m = nm;
        }
        float lse = m + logf(s);
        bool valid = (idx[i] != -100);
        if (valid) {
            accn += diag[i] - lse;
            accd += 1.f;
        }
    }
#pragma unroll
    for (int m = 32; m >= 1; m >>= 1) {
        accn += __shfl_xor(accn, m);
        accd += __shfl_xor(accd, m);
    }
    __shared__ float an[4], ad[4];
    int wave = threadIdx.x >> 6, lane = threadIdx.x & 63;
    if (lane == 0) { an[wave] = accn; ad[wave] = accd; }
    __syncthreads();
    if (threadIdx.x == 0) {
        float n = an[0] + an[1] + an[2] + an[3];
        float d = ad[0] + ad[1] + ad[2] + ad[3];
        out[0] = -n / d;
    }
}

extern "C" void kernel_launch(void* const* d_in, const int* in_sizes, int n_in,
                              void* d_out, int out_size, void* d_ws, size_t ws_size,
                              hipStream_t stream) {
    const float* x      = (const float*)d_in[0];   // [8192][768]
    const float* labels = (const float*)d_in[1];   // [8192][768]
    const int*   lidx   = (const int*)d_in[2];     // [8192]
    const float* vm     = (const float*)d_in[3];   // [8192]
    const float* W1     = (const float*)d_in[4];   // [768][768]
    const float* b1     = (const float*)d_in[5];
    const float* ln_g   = (const float*)d_in[6];
    const float* ln_b   = (const float*)d_in[7];
    const float* Wd     = (const float*)d_in[8];
    const float* b_dec  = (const float*)d_in[9];
    float* out = (float*)d_out;

    const size_t NE = (size_t)ROWS * DPOS;       // 6291456
    const size_t NW = (size_t)DPOS * DPOS;       // 589824
    char* p = (char*)d_ws;
    __bf16* xb   = (__bf16*)p;            p += NE * 2;
    __bf16* labb = (__bf16*)p;            p += NE * 2;
    __bf16* W1b  = (__bf16*)p;            p += NW * 2;
    __bf16* Wdb  = (__bf16*)p;            p += NW * 2;
    float*  h    = (float*)p;             p += NE * 4;
    __bf16* hlnb = (__bf16*)p;            p += NE * 2;
    __bf16* embb = (__bf16*)p;            p += NE * 2;
    float*  pm   = (float*)p;             p += (size_t)ROWS * NSPLIT * 4;
    float*  ps   = (float*)p;             p += (size_t)ROWS * NSPLIT * 4;
    float*  diag = (float*)p;             p += (size_t)ROWS * 4;

    // allow 128 KB dynamic LDS for the 8-phase kernel (idempotent)
    hipFuncSetAttribute((const void*)k_lse8, hipFuncAttributeMaxDynamicSharedMemorySize,
                        131072);

    // convert fp32 -> bf16
    k_f2bf<<<(NE / 4 + 255) / 256, 256, 0, stream>>>(x, xb, (int)NE);
    k_f2bf<<<(NE / 4 + 255) / 256, 256, 0, stream>>>(labels, labb, (int)NE);
    k_f2bf<<<(NW / 4 + 255) / 256, 256, 0, stream>>>(W1, W1b, (int)NW);
    k_f2bf<<<(NW / 4 + 255) / 256, 256, 0, stream>>>(Wd, Wdb, (int)NW);

    // MFM block
    dim3 g1(ROWS / 128, DPOS / 64);
    k_gemm_bt<0><<<g1, 256, 0, stream>>>(xb, W1b, b1, h, nullptr);
    k_ln<<<ROWS, 256, 0, stream>>>(h, ln_g, ln_b, hlnb);
    k_gemm_bt<1><<<g1, 256, 0, stream>>>(hlnb, Wdb, b_dec, nullptr, embb);

    // contrastive loss
    dim3 g2(ROWS / BM, NSPLIT);
    k_lse8<<<g2, 512, 131072, stream>>>(embb, labb, vm, pm, ps);
    k_diag<<<ROWS / 4, 256, 0, stream>>>(embb, labb, diag);
    k_loss<<<1, 256, 0, stream>>>(pm, ps, diag, lidx, out);
}

// Round 4
// 292.084 us; speedup vs baseline: 1.7735x; 1.0061x over previous
//
#include <hip/hip_runtime.h>
#include <hip/hip_bf16.h>
#include <math.h>

#define DPOS 768
#define ROWS 8192           // 32*256
#define NEG_INF_V (-10000.0f)
#define NSPLIT 8

// ---- 8-phase 256^2 geometry for k_lse8 ----
#define BM 256
#define BN 256
#define BK 64
#define CPS (ROWS / NSPLIT)   // cols per split = 1024
#define NCT (CPS / BN)        // col-tiles per block = 4
#define NKT (DPOS / BK)       // K-tiles per col-tile = 12
#define GTOT (NCT * NKT)      // 48
#define TITER (GTOT / 2)      // 24 iterations (2 K-tiles each)

typedef __attribute__((ext_vector_type(8))) __bf16 bf16x8;
typedef __attribute__((ext_vector_type(4))) __bf16 bf16x4;
typedef __attribute__((ext_vector_type(4))) float f32x4;

typedef const __attribute__((address_space(1))) unsigned int* gptr_t;
typedef __attribute__((address_space(3))) unsigned int* lptr_t;

#define SBAR() do { __builtin_amdgcn_sched_barrier(0); __builtin_amdgcn_s_barrier(); __builtin_amdgcn_sched_barrier(0); } while (0)
#define VMW(N) do { __builtin_amdgcn_sched_barrier(0); asm volatile("s_waitcnt vmcnt(" #N ")" ::: "memory"); __builtin_amdgcn_sched_barrier(0); } while (0)

// ---------------- fp32 -> bf16 conversion (two arrays per launch) ----------------
__global__ __launch_bounds__(256) void k_f2bf2(const float* __restrict__ a,
                                               const float* __restrict__ b,
                                               __bf16* __restrict__ da,
                                               __bf16* __restrict__ db, int n) {
    int i = (blockIdx.x * blockDim.x + threadIdx.x) * 4;
    const float* s = (i < n) ? a : b;
    __bf16* d = (i < n) ? da : db;
    int j = (i < n) ? i : i - n;
    float4 v = *(const float4*)(s + j);
    bf16x4 o = {(__bf16)v.x, (__bf16)v.y, (__bf16)v.z, (__bf16)v.w};
    *(bf16x4*)(d + j) = o;
}

// ---------------- GEMM C = A * B^T  (+bias, epilogue), bf16 out ----------------
// MODE 0: out = gelu(acc + bias)   MODE 1: out = acc + bias
template <int MODE>
__global__ __launch_bounds__(256) void k_gemm_bt(const __bf16* __restrict__ A,
                                                 const __bf16* __restrict__ B,
                                                 const float* __restrict__ bias,
                                                 __bf16* __restrict__ outB) {
    const int lane = threadIdx.x & 63;
    const int wave = threadIdx.x >> 6;
    const int wr = wave >> 1, wc = wave & 1;  // 2x2 waves -> 128x64 block tile
    const int row0 = blockIdx.x * 128 + wr * 64;
    const int col0 = blockIdx.y * 64 + wc * 32;
    const int lr = lane & 15;
    const int lk = (lane >> 4) * 8;

    f32x4 acc[4][2] = {};
    for (int k0 = 0; k0 < DPOS; k0 += 32) {
        bf16x8 a[4], b[2];
#pragma unroll
        for (int f = 0; f < 4; ++f)
            a[f] = *(const bf16x8*)(A + (size_t)(row0 + f * 16 + lr) * DPOS + k0 + lk);
#pragma unroll
        for (int f = 0; f < 2; ++f)
            b[f] = *(const bf16x8*)(B + (size_t)(col0 + f * 16 + lr) * DPOS + k0 + lk);
#pragma unroll
        for (int i = 0; i < 4; ++i)
#pragma unroll
            for (int j = 0; j < 2; ++j)
                acc[i][j] = __builtin_amdgcn_mfma_f32_16x16x32_bf16(a[i], b[j], acc[i][j], 0, 0, 0);
    }
    const int rr = (lane >> 4) * 4;
#pragma unroll
    for (int i = 0; i < 4; ++i)
#pragma unroll
        for (int j = 0; j < 2; ++j) {
            int col = col0 + j * 16 + lr;
            float bv = bias[col];
#pragma unroll
            for (int v = 0; v < 4; ++v) {
                int row = row0 + i * 16 + rr + v;
                float val = acc[i][j][v] + bv;
                if (MODE == 0)
                    val = 0.5f * val * (1.0f + erff(val * 0.70710678118654752f));
                outB[(size_t)row * DPOS + col] = (__bf16)val;
            }
        }
}

// ---------------- LayerNorm over last dim (768), one block per row, bf16 in/out ----------------
__global__ __launch_bounds__(256) void k_ln(const __bf16* __restrict__ h,
                                            const float* __restrict__ g,
                                            const float* __restrict__ bta,
                                            __bf16* __restrict__ out) {
    int row = blockIdx.x;
    const __bf16* hr = h + (size_t)row * DPOS;
    float v[3], s = 0.f, sq = 0.f;
#pragma unroll
    for (int t = 0; t < 3; ++t) {
        v[t] = (float)hr[threadIdx.x + t * 256];
        s += v[t];
        sq += v[t] * v[t];
    }
#pragma unroll
    for (int m = 32; m >= 1; m >>= 1) {
        s += __shfl_xor(s, m);
        sq += __shfl_xor(sq, m);
    }
    __shared__ float ss[4], sqq[4];
    int wave = threadIdx.x >> 6, lane = threadIdx.x & 63;
    if (lane == 0) { ss[wave] = s; sqq[wave] = sq; }
    __syncthreads();
    s = ss[0] + ss[1] + ss[2] + ss[3];
    sq = sqq[0] + sqq[1] + sqq[2] + sqq[3];
    float mu = s * (1.0f / DPOS);
    float var = sq * (1.0f / DPOS) - mu * mu;
    float r = rsqrtf(var + 1e-12f);
#pragma unroll
    for (int t = 0; t < 3; ++t) {
        int c = threadIdx.x + t * 256;
        out[(size_t)row * DPOS + c] = (__bf16)((v[t] - mu) * r * g[c] + bta[c]);
    }
}

// ---------------- fused logits + row-wise logsumexp, 8-phase 256^2 schedule ----------------
// 1-D grid 256 blocks: split = bid & 7 (all same-split blocks -> same XCD -> L-panel
// (1.5 MB) is L2-resident), rowblk = bid >> 3.
// LDS (dynamic 128 KB): slot s at s*65536: A[256][64] at +0, B[256][64] at +32768.
// XOR-swizzle byte ^= ((row&7)<<4); linear dest + pre-swizzled global source.
// Stage rotation (region staged 3-5 phases before its VMW):
//   ph1: s1A-hi(g1)   ph3: s0B-lo(g0+2)  ph4: s0B-hi,s0A-lo(g0+2) VMW(6)
//   ph5: s0A-hi(g0+2) ph7: s1B-lo(g1+2)  ph8: s1B-hi,s1A-lo(g1+2) VMW(6)
__global__ __launch_bounds__(512, 1) void k_lse8(const __bf16* __restrict__ E,
                                                 const __bf16* __restrict__ L,
                                                 const float* __restrict__ vm,
                                                 float* __restrict__ pm,
                                                 float* __restrict__ ps) {
    extern __shared__ char lds[];
    __shared__ float smm[2][4][128], sms[2][4][128];
    __shared__ float svm[CPS];

    const int tid = threadIdx.x;
    const int lane = tid & 63;
    const int wave = tid >> 6;
    const int wr = wave >> 2, wc = wave & 3;
    const int lr = lane & 15;
    const int lk = (lane >> 4) * 8;
    const int rr = (lane >> 4) * 4;
    const int bid = blockIdx.x;
    const int split = bid & 7;
    const int row0 = (bid >> 3) * BM;

    // column-mask values for this split -> LDS (epilogue reads via ds_read, no vmcnt)
    svm[tid] = vm[split * CPS + tid];
    svm[tid + 512] = vm[split * CPS + tid + 512];

    // ---- row-mask bits: 32 rows per lane ----
    unsigned mrow = 0;
#pragma unroll
    for (int mi = 0; mi < 8; ++mi) {
        float4 mv = *(const float4*)(vm + row0 + wr * 128 + mi * 16 + rr);
        if (mv.x != 0.f) mrow |= 1u << (mi * 4 + 0);
        if (mv.y != 0.f) mrow |= 1u << (mi * 4 + 1);
        if (mv.z != 0.f) mrow |= 1u << (mi * 4 + 2);
        if (mv.w != 0.f) mrow |= 1u << (mi * 4 + 3);
    }

    // ---- staging geometry: each half-tile (128 rows x 64 K) = 2 x 16B per thread ----
    const int o0 = tid * 16, o1 = o0 + 8192;
    const int r0s = o0 >> 7, r1s = o1 >> 7;
    const int c0s = (o0 & 127) ^ ((r0s & 7) << 4);
    const int c1s = (o1 & 127) ^ ((r1s & 7) << 4);

    const char* Eb = (const char*)E + (size_t)row0 * (DPOS * 2);
    const char* Lb = (const char*)L;

    auto stageA = [&](int slot, int half, int g) {
        char* dst = lds + slot * 65536 + half * 16384;
        const char* src = Eb + (size_t)(half * 128) * (DPOS * 2) + (size_t)(g % NKT) * 128;
        __builtin_amdgcn_global_load_lds((gptr_t)(src + (size_t)r0s * (DPOS * 2) + c0s),
                                         (lptr_t)(dst + o0), 16, 0, 0);
        __builtin_amdgcn_global_load_lds((gptr_t)(src + (size_t)r1s * (DPOS * 2) + c1s),
                                         (lptr_t)(dst + o1), 16, 0, 0);
    };
    auto stageB = [&](int slot, int half, int g) {
        char* dst = lds + slot * 65536 + 32768 + half * 16384;
        const char* src = Lb + (size_t)(split * CPS + (g / NKT) * BN + half * 128) * (DPOS * 2)
                             + (size_t)(g % NKT) * 128;
        __builtin_amdgcn_global_load_lds((gptr_t)(src + (size_t)r0s * (DPOS * 2) + c0s),
                                         (lptr_t)(dst + o0), 16, 0, 0);
        __builtin_amdgcn_global_load_lds((gptr_t)(src + (size_t)r1s * (DPOS * 2) + c1s),
                                         (lptr_t)(dst + o1), 16, 0, 0);
    };

    bf16x8 a[4][2], bLo[2][2], bHi[2][2];
    f32x4 acc[8][4];
#pragma unroll
    for (int mi = 0; mi < 8; ++mi)
#pragma unroll
        for (int ni = 0; ni < 4; ++ni) acc[mi][ni] = (f32x4){0.f, 0.f, 0.f, 0.f};

    auto readA = [&](int slot, int mh) {
#pragma unroll
        for (int mi = 0; mi < 4; ++mi) {
            int r = wr * 128 + mh * 64 + mi * 16 + lr;
            int base = slot * 65536 + r * 128;
            int sw = (r & 7) << 4;
            a[mi][0] = *(const bf16x8*)(lds + base + ((lk * 2) ^ sw));
            a[mi][1] = *(const bf16x8*)(lds + base + (((32 + lk) * 2) ^ sw));
        }
    };
    auto readB = [&](int slot, int nh, bf16x8 (&dst)[2][2]) {
#pragma unroll
        for (int ni = 0; ni < 2; ++ni) {
            int r = wc * 64 + nh * 32 + ni * 16 + lr;
            int base = slot * 65536 + 32768 + r * 128;
            int sw = (r & 7) << 4;
            dst[ni][0] = *(const bf16x8*)(lds + base + ((lk * 2) ^ sw));
            dst[ni][1] = *(const bf16x8*)(lds + base + (((32 + lk) * 2) ^ sw));
        }
    };

#define MFMAQ(MI0, NI0, B) do { \
    __builtin_amdgcn_s_setprio(1); \
    _Pragma("unroll") \
    for (int mi = 0; mi < 4; ++mi) \
        _Pragma("unroll") \
        for (int ni = 0; ni < 2; ++ni) \
            _Pragma("unroll") \
            for (int kk = 0; kk < 2; ++kk) \
                acc[MI0 + mi][NI0 + ni] = __builtin_amdgcn_mfma_f32_16x16x32_bf16( \
                    a[mi][kk], B[ni][kk], acc[MI0 + mi][NI0 + ni], 0, 0, 0); \
    __builtin_amdgcn_s_setprio(0); \
} while (0)

    float Mrun = -1e30f, Srun = 0.f;

    // ---- prologue: s0 A+B (g=0), s1 B (g=1), s1 A-lo (g=1) = 14 loads ----
    stageA(0, 0, 0); stageA(0, 1, 0); stageB(0, 0, 0); stageB(0, 1, 0);
    stageB(1, 0, 1); stageB(1, 1, 1); stageA(1, 0, 1);
    asm volatile("s_waitcnt lgkmcnt(0)");   // svm writes visible before barrier
    VMW(6);
    SBAR();

#pragma unroll 1
    for (int i = 0; i < TITER; ++i) {
        const int g0 = 2 * i, g1 = 2 * i + 1;
        const bool nt = (i + 1 < TITER);

        // ph1: read s0 A-mh0 + B-nh0; stage s1A-hi (g1)
        readA(0, 0); readB(0, 0, bLo);
        stageA(1, 1, g1);
        SBAR(); MFMAQ(0, 0, bLo); SBAR();
        // ph2: read s0 B-nh1
        readB(0, 1, bHi);
        SBAR(); MFMAQ(0, 2, bHi); SBAR();
        // ph3: read s0 A-mh1; stage s0B-lo (g0+2)
        readA(0, 1);
        if (nt) stageB(0, 0, g0 + 2);
        SBAR(); MFMAQ(4, 0, bLo); SBAR();
        // ph4: stage s0B-hi + s0A-lo (g0+2); counted wait releases s1
        if (nt) { stageB(0, 1, g0 + 2); stageA(0, 0, g0 + 2); VMW(6); }
        else { VMW(0); }
        SBAR(); MFMAQ(4, 2, bHi); SBAR();
        // ph5: read s1 A-mh0 + B-nh0; stage s0A-hi (g0+2)
        readA(1, 0); readB(1, 0, bLo);
        if (nt) stageA(0, 1, g0 + 2);
        SBAR(); MFMAQ(0, 0, bLo); SBAR();
        // ph6: read s1 B-nh1
        readB(1, 1, bHi);
        SBAR(); MFMAQ(0, 2, bHi); SBAR();
        // ph7: read s1 A-mh1; stage s1B-lo (g1+2)
        readA(1, 1);
        if (nt) stageB(1, 0, g1 + 2);
        SBAR(); MFMAQ(4, 0, bLo); SBAR();
        // ph8: stage s1B-hi + s1A-lo (g1+2); counted wait releases s0
        if (nt) { stageB(1, 1, g1 + 2); stageA(1, 0, g1 + 2); VMW(6); }
        SBAR(); MFMAQ(4, 2, bHi); SBAR();

        // ---- col-tile epilogue: fused online-softmax over this 256x256 logits tile ----
        if ((i % (NKT / 2)) == (NKT / 2 - 1)) {
            const int ct = i / (NKT / 2);
            float cmv[4];
#pragma unroll
            for (int ni = 0; ni < 4; ++ni)
                cmv[ni] = svm[ct * BN + wc * 64 + ni * 16 + lr];
#pragma unroll
            for (int mi = 0; mi < 8; ++mi) {
#pragma unroll
                for (int v = 0; v < 4; ++v) {
                    bool rv = (mrow >> (mi * 4 + v)) & 1u;
                    float x0 = acc[mi][0][v] + ((rv && cmv[0] == 0.f) ? NEG_INF_V : 0.f);
                    float x1 = acc[mi][1][v] + ((rv && cmv[1] == 0.f) ? NEG_INF_V : 0.f);
                    float x2 = acc[mi][2][v] + ((rv && cmv[2] == 0.f) ? NEG_INF_V : 0.f);
                    float x3 = acc[mi][3][v] + ((rv && cmv[3] == 0.f) ? NEG_INF_V : 0.f);
                    float m4 = fmaxf(fmaxf(x0, x1), fmaxf(x2, x3));
                    float s4 = __expf(x0 - m4) + __expf(x1 - m4) +
                               __expf(x2 - m4) + __expf(x3 - m4);
#pragma unroll
                    for (int d = 1; d < 16; d <<= 1) {
                        float mo = __shfl_xor(m4, d);
                        float so = __shfl_xor(s4, d);
                        float nm = fmaxf(m4, mo);
                        s4 = s4 * __expf(m4 - nm) + so * __expf(mo - nm);
                        m4 = nm;
                    }
                    if (lr == 0) {
                        smm[wr][wc][mi * 16 + rr + v] = m4;
                        sms[wr][wc][mi * 16 + rr + v] = s4;
                    }
                }
#pragma unroll
                for (int ni = 0; ni < 4; ++ni) acc[mi][ni] = (f32x4){0.f, 0.f, 0.f, 0.f};
            }
            asm volatile("s_waitcnt lgkmcnt(0)");
            SBAR();
            if (tid < 256) {
                int rl = tid & 127, wrh = tid >> 7;
                float m = smm[wrh][0][rl], s = sms[wrh][0][rl];
#pragma unroll
                for (int w = 1; w < 4; ++w) {
                    float mo = smm[wrh][w][rl], so = sms[wrh][w][rl];
                    float nm = fmaxf(m, mo);
                    s = s * __expf(m - nm) + so * __expf(mo - nm);
                    m = nm;
                }
                float nm = fmaxf(Mrun, m);
                Srun = Srun * __expf(Mrun - nm) + s * __expf(m - nm);
                Mrun = nm;
            }
            SBAR();
        }
    }
#undef MFMAQ

    if (tid < 256) {
        int rl = tid & 127, wrh = tid >> 7;
        size_t idx = (size_t)(row0 + wrh * 128 + rl) * NSPLIT + split;
        pm[idx] = Mrun;
        ps[idx] = Srun;
    }
}

// ---------------- diagonal: diag[i] = dot(emb_i, labels_i) ----------------
__global__ __launch_bounds__(256) void k_diag(const __bf16* __restrict__ E,
                                              const __bf16* __restrict__ L,
                                              float* __restrict__ diag) {
    int wave = threadIdx.x >> 6, lane = threadIdx.x & 63;
    int row = blockIdx.x * 4 + wave;
    const __bf16* e = E + (size_t)row * DPOS;
    const __bf16* l = L + (size_t)row * DPOS;
    float s = 0.f;
    for (int k = lane * 8; k < DPOS; k += 64 * 8) {
        bf16x8 a = *(const bf16x8*)(e + k);
        bf16x8 b = *(const bf16x8*)(l + k);
#pragma unroll
        for (int j = 0; j < 8; ++j) s += (float)a[j] * (float)b[j];
    }
#pragma unroll
    for (int m = 32; m >= 1; m >>= 1) s += __shfl_xor(s, m);
    if (lane == 0) diag[row] = s;
}

// ---------------- combine partials + masked mean ----------------
__global__ __launch_bounds__(256) void k_loss(const float* __restrict__ pm,
                                              const float* __restrict__ ps,
                                              const float* __restrict__ diag,
                                              const int* __restrict__ idx,
                                              float* __restrict__ out) {
    float accn = 0.f, accd = 0.f;
    for (int i = threadIdx.x; i < ROWS; i += 256) {
        float m = pm[i * NSPLIT + 0], s = ps[i * NSPLIT + 0];
#pragma unroll
        for (int c = 1; c < NSPLIT; ++c) {
            float mo = pm[i * NSPLIT + c], so = ps[i * NSPLIT + c];
            float nm = fmaxf(m, mo);
            s = s * __expf(m - nm) + so * __expf(mo - nm);
            m = nm;
        }
        float lse = m + logf(s);
        bool valid = (idx[i] != -100);
        if (valid) {
            accn += diag[i] - lse;
            accd += 1.f;
        }
    }
#pragma unroll
    for (int m = 32; m >= 1; m >>= 1) {
        accn += __shfl_xor(accn, m);
        accd += __shfl_xor(accd, m);
    }
    __shared__ float an[4], ad[4];
    int wave = threadIdx.x >> 6, lane = threadIdx.x & 63;
    if (lane == 0) { an[wave] = accn; ad[wave] = accd; }
    __syncthreads();
    if (threadIdx.x == 0) {
        float n = an[0] + an[1] + an[2] + an[3];
        float d = ad[0] + ad[1] + ad[2] + ad[3];
        out[0] = -n / d;
    }
}

extern "C" void kernel_launch(void* const* d_in, const int* in_sizes, int n_in,
                              void* d_out, int out_size, void* d_ws, size_t ws_size,
                              hipStream_t stream) {
    const float* x      = (const float*)d_in[0];   // [8192][768]
    const float* labels = (const float*)d_in[1];   // [8192][768]
    const int*   lidx   = (const int*)d_in[2];     // [8192]
    const float* vm     = (const float*)d_in[3];   // [8192]
    const float* W1     = (const float*)d_in[4];   // [768][768]
    const float* b1     = (const float*)d_in[5];
    const float* ln_g   = (const float*)d_in[6];
    const float* ln_b   = (const float*)d_in[7];
    const float* Wd     = (const float*)d_in[8];
    const float* b_dec  = (const float*)d_in[9];
    float* out = (float*)d_out;

    const size_t NE = (size_t)ROWS * DPOS;       // 6291456
    const size_t NW = (size_t)DPOS * DPOS;       // 589824
    char* p = (char*)d_ws;
    __bf16* xb   = (__bf16*)p;            p += NE * 2;
    __bf16* labb = (__bf16*)p;            p += NE * 2;
    __bf16* W1b  = (__bf16*)p;            p += NW * 2;
    __bf16* Wdb  = (__bf16*)p;            p += NW * 2;
    __bf16* hb   = (__bf16*)p;            p += NE * 2;
    __bf16* hlnb = (__bf16*)p;            p += NE * 2;
    __bf16* embb = (__bf16*)p;            p += NE * 2;
    float*  pm   = (float*)p;             p += (size_t)ROWS * NSPLIT * 4;
    float*  ps   = (float*)p;             p += (size_t)ROWS * NSPLIT * 4;
    float*  diag = (float*)p;             p += (size_t)ROWS * 4;

    hipFuncSetAttribute((const void*)k_lse8, hipFuncAttributeMaxDynamicSharedMemorySize,
                        131072);

    // convert fp32 -> bf16 (x+labels in one launch, W1+Wd in another)
    k_f2bf2<<<(2 * NE / 4) / 256, 256, 0, stream>>>(x, labels, xb, labb, (int)NE);
    k_f2bf2<<<(2 * NW / 4) / 256, 256, 0, stream>>>(W1, Wd, W1b, Wdb, (int)NW);

    // MFM block
    dim3 g1(ROWS / 128, DPOS / 64);
    k_gemm_bt<0><<<g1, 256, 0, stream>>>(xb, W1b, b1, hb);
    k_ln<<<ROWS, 256, 0, stream>>>(hb, ln_g, ln_b, hlnb);
    k_gemm_bt<1><<<g1, 256, 0, stream>>>(hlnb, Wdb, b_dec, embb);

    // contrastive loss (1-D grid, XCD-aligned split mapping)
    k_lse8<<<ROWS / BM * NSPLIT, 512, 131072, stream>>>(embb, labb, vm, pm, ps);
    k_diag<<<ROWS / 4, 256, 0, stream>>>(embb, labb, diag);
    k_loss<<<1, 256, 0, stream>>>(pm, ps, diag, lidx, out);
}

// Round 5
// 291.271 us; speedup vs baseline: 1.7784x; 1.0028x over previous
//
#include <hip/hip_runtime.h>
#include <hip/hip_bf16.h>
#include <math.h>

#define DPOS 768
#define ROWS 8192           // 32*256
#define NEG_INF_V (-10000.0f)
#define NSPLIT 8

// ---- 8-phase 256^2 geometry for k_lse8 ----
#define BM 256
#define BN 256
#define BK 64
#define CPS (ROWS / NSPLIT)   // cols per split = 1024
#define NCT (CPS / BN)        // col-tiles per block = 4
#define NKT (DPOS / BK)       // K-tiles per col-tile = 12
#define GTOT (NCT * NKT)      // 48
#define TITER (GTOT / 2)      // 24 iterations (2 K-tiles each)

typedef __attribute__((ext_vector_type(8))) __bf16 bf16x8;
typedef __attribute__((ext_vector_type(4))) __bf16 bf16x4;
typedef __attribute__((ext_vector_type(4))) float f32x4;

typedef const __attribute__((address_space(1))) unsigned int* gptr_t;
typedef __attribute__((address_space(3))) unsigned int* lptr_t;

// R5 change: NO sched_barrier walls (m141 signature: order-pinning defeated the
// compiler scheduler). Plain s_barrier (m201 pattern); vmcnt with memory clobber
// keeps the counted-vmcnt accounting exact (VMEM ops cannot cross the asm).
#define SBAR() __builtin_amdgcn_s_barrier()
#define VMW(N) asm volatile("s_waitcnt vmcnt(" #N ")" ::: "memory")

// ---------------- fp32 -> bf16 conversion (two arrays per launch) ----------------
__global__ __launch_bounds__(256) void k_f2bf2(const float* __restrict__ a,
                                               const float* __restrict__ b,
                                               __bf16* __restrict__ da,
                                               __bf16* __restrict__ db, int n) {
    int i = (blockIdx.x * blockDim.x + threadIdx.x) * 4;
    const float* s = (i < n) ? a : b;
    __bf16* d = (i < n) ? da : db;
    int j = (i < n) ? i : i - n;
    float4 v = *(const float4*)(s + j);
    bf16x4 o = {(__bf16)v.x, (__bf16)v.y, (__bf16)v.z, (__bf16)v.w};
    *(bf16x4*)(d + j) = o;
}

// ---------------- GEMM C = A * B^T  (+bias, epilogue), bf16 out ----------------
// MODE 0: out = gelu(acc + bias)   MODE 1: out = acc + bias
template <int MODE>
__global__ __launch_bounds__(256) void k_gemm_bt(const __bf16* __restrict__ A,
                                                 const __bf16* __restrict__ B,
                                                 const float* __restrict__ bias,
                                                 __bf16* __restrict__ outB) {
    const int lane = threadIdx.x & 63;
    const int wave = threadIdx.x >> 6;
    const int wr = wave >> 1, wc = wave & 1;  // 2x2 waves -> 128x64 block tile
    const int row0 = blockIdx.x * 128 + wr * 64;
    const int col0 = blockIdx.y * 64 + wc * 32;
    const int lr = lane & 15;
    const int lk = (lane >> 4) * 8;

    f32x4 acc[4][2] = {};
    for (int k0 = 0; k0 < DPOS; k0 += 32) {
        bf16x8 a[4], b[2];
#pragma unroll
        for (int f = 0; f < 4; ++f)
            a[f] = *(const bf16x8*)(A + (size_t)(row0 + f * 16 + lr) * DPOS + k0 + lk);
#pragma unroll
        for (int f = 0; f < 2; ++f)
            b[f] = *(const bf16x8*)(B + (size_t)(col0 + f * 16 + lr) * DPOS + k0 + lk);
#pragma unroll
        for (int i = 0; i < 4; ++i)
#pragma unroll
            for (int j = 0; j < 2; ++j)
                acc[i][j] = __builtin_amdgcn_mfma_f32_16x16x32_bf16(a[i], b[j], acc[i][j], 0, 0, 0);
    }
    const int rr = (lane >> 4) * 4;
#pragma unroll
    for (int i = 0; i < 4; ++i)
#pragma unroll
        for (int j = 0; j < 2; ++j) {
            int col = col0 + j * 16 + lr;
            float bv = bias[col];
#pragma unroll
            for (int v = 0; v < 4; ++v) {
                int row = row0 + i * 16 + rr + v;
                float val = acc[i][j][v] + bv;
                if (MODE == 0)
                    val = 0.5f * val * (1.0f + erff(val * 0.70710678118654752f));
                outB[(size_t)row * DPOS + col] = (__bf16)val;
            }
        }
}

// ---------------- LayerNorm over last dim (768), one block per row, bf16 in/out ----------------
__global__ __launch_bounds__(256) void k_ln(const __bf16* __restrict__ h,
                                            const float* __restrict__ g,
                                            const float* __restrict__ bta,
                                            __bf16* __restrict__ out) {
    int row = blockIdx.x;
    const __bf16* hr = h + (size_t)row * DPOS;
    float v[3], s = 0.f, sq = 0.f;
#pragma unroll
    for (int t = 0; t < 3; ++t) {
        v[t] = (float)hr[threadIdx.x + t * 256];
        s += v[t];
        sq += v[t] * v[t];
    }
#pragma unroll
    for (int m = 32; m >= 1; m >>= 1) {
        s += __shfl_xor(s, m);
        sq += __shfl_xor(sq, m);
    }
    __shared__ float ss[4], sqq[4];
    int wave = threadIdx.x >> 6, lane = threadIdx.x & 63;
    if (lane == 0) { ss[wave] = s; sqq[wave] = sq; }
    __syncthreads();
    s = ss[0] + ss[1] + ss[2] + ss[3];
    sq = sqq[0] + sqq[1] + sqq[2] + sqq[3];
    float mu = s * (1.0f / DPOS);
    float var = sq * (1.0f / DPOS) - mu * mu;
    float r = rsqrtf(var + 1e-12f);
#pragma unroll
    for (int t = 0; t < 3; ++t) {
        int c = threadIdx.x + t * 256;
        out[(size_t)row * DPOS + c] = (__bf16)((v[t] - mu) * r * g[c] + bta[c]);
    }
}

// ---------------- fused logits + row-wise logsumexp, 8-phase 256^2 schedule ----------------
// 1-D grid 256 blocks: split = bid & 7, rowblk = bid >> 3.
// LDS (dynamic 128 KB): slot s at s*65536: A[256][64] at +0, B[256][64] at +32768.
// XOR-swizzle byte ^= ((row&7)<<4); linear dest + pre-swizzled global source.
// Stage rotation (write-after-read audited: every stage targets a region whose
// last ds_read was consumed in an earlier phase, behind a barrier):
//   ph1: s1A-hi(g1)   ph3: s0B-lo(g0+2)  ph4: s0B-hi,s0A-lo(g0+2) VMW(6)
//   ph5: s0A-hi(g0+2) ph7: s1B-lo(g1+2)  ph8: s1B-hi,s1A-lo(g1+2) VMW(6)
__global__ __launch_bounds__(512, 1) void k_lse8(const __bf16* __restrict__ E,
                                                 const __bf16* __restrict__ L,
                                                 const float* __restrict__ vm,
                                                 float* __restrict__ pm,
                                                 float* __restrict__ ps) {
    extern __shared__ char lds[];
    __shared__ float smm[2][4][128], sms[2][4][128];
    __shared__ float svm[CPS];

    const int tid = threadIdx.x;
    const int lane = tid & 63;
    const int wave = tid >> 6;
    const int wr = wave >> 2, wc = wave & 3;
    const int lr = lane & 15;
    const int lk = (lane >> 4) * 8;
    const int rr = (lane >> 4) * 4;
    const int bid = blockIdx.x;
    const int split = bid & 7;
    const int row0 = (bid >> 3) * BM;

    // column-mask values for this split -> LDS (epilogue reads via ds_read, no vmcnt)
    svm[tid] = vm[split * CPS + tid];
    svm[tid + 512] = vm[split * CPS + tid + 512];

    // ---- row-mask bits: 32 rows per lane ----
    unsigned mrow = 0;
#pragma unroll
    for (int mi = 0; mi < 8; ++mi) {
        float4 mv = *(const float4*)(vm + row0 + wr * 128 + mi * 16 + rr);
        if (mv.x != 0.f) mrow |= 1u << (mi * 4 + 0);
        if (mv.y != 0.f) mrow |= 1u << (mi * 4 + 1);
        if (mv.z != 0.f) mrow |= 1u << (mi * 4 + 2);
        if (mv.w != 0.f) mrow |= 1u << (mi * 4 + 3);
    }

    // ---- staging geometry: each half-tile (128 rows x 64 K) = 2 x 16B per thread ----
    const int o0 = tid * 16, o1 = o0 + 8192;
    const int r0s = o0 >> 7, r1s = o1 >> 7;
    const int c0s = (o0 & 127) ^ ((r0s & 7) << 4);
    const int c1s = (o1 & 127) ^ ((r1s & 7) << 4);

    const char* Eb = (const char*)E + (size_t)row0 * (DPOS * 2);
    const char* Lb = (const char*)L;

    auto stageA = [&](int slot, int half, int g) {
        char* dst = lds + slot * 65536 + half * 16384;
        const char* src = Eb + (size_t)(half * 128) * (DPOS * 2) + (size_t)(g % NKT) * 128;
        __builtin_amdgcn_global_load_lds((gptr_t)(src + (size_t)r0s * (DPOS * 2) + c0s),
                                         (lptr_t)(dst + o0), 16, 0, 0);
        __builtin_amdgcn_global_load_lds((gptr_t)(src + (size_t)r1s * (DPOS * 2) + c1s),
                                         (lptr_t)(dst + o1), 16, 0, 0);
    };
    auto stageB = [&](int slot, int half, int g) {
        char* dst = lds + slot * 65536 + 32768 + half * 16384;
        const char* src = Lb + (size_t)(split * CPS + (g / NKT) * BN + half * 128) * (DPOS * 2)
                             + (size_t)(g % NKT) * 128;
        __builtin_amdgcn_global_load_lds((gptr_t)(src + (size_t)r0s * (DPOS * 2) + c0s),
                                         (lptr_t)(dst + o0), 16, 0, 0);
        __builtin_amdgcn_global_load_lds((gptr_t)(src + (size_t)r1s * (DPOS * 2) + c1s),
                                         (lptr_t)(dst + o1), 16, 0, 0);
    };

    bf16x8 a[4][2], bLo[2][2], bHi[2][2];
    f32x4 acc[8][4];
#pragma unroll
    for (int mi = 0; mi < 8; ++mi)
#pragma unroll
        for (int ni = 0; ni < 4; ++ni) acc[mi][ni] = (f32x4){0.f, 0.f, 0.f, 0.f};

    auto readA = [&](int slot, int mh) {
#pragma unroll
        for (int mi = 0; mi < 4; ++mi) {
            int r = wr * 128 + mh * 64 + mi * 16 + lr;
            int base = slot * 65536 + r * 128;
            int sw = (r & 7) << 4;
            a[mi][0] = *(const bf16x8*)(lds + base + ((lk * 2) ^ sw));
            a[mi][1] = *(const bf16x8*)(lds + base + (((32 + lk) * 2) ^ sw));
        }
    };
    auto readB = [&](int slot, int nh, bf16x8 (&dst)[2][2]) {
#pragma unroll
        for (int ni = 0; ni < 2; ++ni) {
            int r = wc * 64 + nh * 32 + ni * 16 + lr;
            int base = slot * 65536 + 32768 + r * 128;
            int sw = (r & 7) << 4;
            dst[ni][0] = *(const bf16x8*)(lds + base + ((lk * 2) ^ sw));
            dst[ni][1] = *(const bf16x8*)(lds + base + (((32 + lk) * 2) ^ sw));
        }
    };

#define MFMAQ(MI0, NI0, B) do { \
    __builtin_amdgcn_s_setprio(1); \
    _Pragma("unroll") \
    for (int mi = 0; mi < 4; ++mi) \
        _Pragma("unroll") \
        for (int ni = 0; ni < 2; ++ni) \
            _Pragma("unroll") \
            for (int kk = 0; kk < 2; ++kk) \
                acc[MI0 + mi][NI0 + ni] = __builtin_amdgcn_mfma_f32_16x16x32_bf16( \
                    a[mi][kk], B[ni][kk], acc[MI0 + mi][NI0 + ni], 0, 0, 0); \
    __builtin_amdgcn_s_setprio(0); \
} while (0)

    float Mrun = -1e30f, Srun = 0.f;

    // ---- prologue: s0 A+B (g=0), s1 B (g=1), s1 A-lo (g=1) = 14 loads ----
    stageA(0, 0, 0); stageA(0, 1, 0); stageB(0, 0, 0); stageB(0, 1, 0);
    stageB(1, 0, 1); stageB(1, 1, 1); stageA(1, 0, 1);
    asm volatile("s_waitcnt lgkmcnt(0)");   // svm writes visible before barrier
    VMW(6);
    SBAR();

#pragma unroll 1
    for (int i = 0; i < TITER; ++i) {
        const int g0 = 2 * i, g1 = 2 * i + 1;
        const bool nt = (i + 1 < TITER);

        // ph1: read s0 A-mh0 + B-nh0; stage s1A-hi (g1)
        readA(0, 0); readB(0, 0, bLo);
        stageA(1, 1, g1);
        SBAR(); MFMAQ(0, 0, bLo); SBAR();
        // ph2: read s0 B-nh1
        readB(0, 1, bHi);
        SBAR(); MFMAQ(0, 2, bHi); SBAR();
        // ph3: read s0 A-mh1; stage s0B-lo (g0+2)
        readA(0, 1);
        if (nt) stageB(0, 0, g0 + 2);
        SBAR(); MFMAQ(4, 0, bLo); SBAR();
        // ph4: stage s0B-hi + s0A-lo (g0+2); counted wait releases s1
        if (nt) { stageB(0, 1, g0 + 2); stageA(0, 0, g0 + 2); VMW(6); }
        else { VMW(0); }
        SBAR(); MFMAQ(4, 2, bHi); SBAR();
        // ph5: read s1 A-mh0 + B-nh0; stage s0A-hi (g0+2)
        readA(1, 0); readB(1, 0, bLo);
        if (nt) stageA(0, 1, g0 + 2);
        SBAR(); MFMAQ(0, 0, bLo); SBAR();
        // ph6: read s1 B-nh1
        readB(1, 1, bHi);
        SBAR(); MFMAQ(0, 2, bHi); SBAR();
        // ph7: read s1 A-mh1; stage s1B-lo (g1+2)
        readA(1, 1);
        if (nt) stageB(1, 0, g1 + 2);
        SBAR(); MFMAQ(4, 0, bLo); SBAR();
        // ph8: stage s1B-hi + s1A-lo (g1+2); counted wait releases s0
        if (nt) { stageB(1, 1, g1 + 2); stageA(1, 0, g1 + 2); VMW(6); }
        SBAR(); MFMAQ(4, 2, bHi); SBAR();

        // ---- col-tile epilogue: fused online-softmax over this 256x256 logits tile ----
        if ((i % (NKT / 2)) == (NKT / 2 - 1)) {
            const int ct = i / (NKT / 2);
            float cmv[4];
#pragma unroll
            for (int ni = 0; ni < 4; ++ni)
                cmv[ni] = svm[ct * BN + wc * 64 + ni * 16 + lr];
#pragma unroll
            for (int mi = 0; mi < 8; ++mi) {
#pragma unroll
                for (int v = 0; v < 4; ++v) {
                    bool rv = (mrow >> (mi * 4 + v)) & 1u;
                    float x0 = acc[mi][0][v] + ((rv && cmv[0] == 0.f) ? NEG_INF_V : 0.f);
                    float x1 = acc[mi][1][v] + ((rv && cmv[1] == 0.f) ? NEG_INF_V : 0.f);
                    float x2 = acc[mi][2][v] + ((rv && cmv[2] == 0.f) ? NEG_INF_V : 0.f);
                    float x3 = acc[mi][3][v] + ((rv && cmv[3] == 0.f) ? NEG_INF_V : 0.f);
                    float m4 = fmaxf(fmaxf(x0, x1), fmaxf(x2, x3));
                    float s4 = __expf(x0 - m4) + __expf(x1 - m4) +
                               __expf(x2 - m4) + __expf(x3 - m4);
#pragma unroll
                    for (int d = 1; d < 16; d <<= 1) {
                        float mo = __shfl_xor(m4, d);
                        float so = __shfl_xor(s4, d);
                        float nm = fmaxf(m4, mo);
                        s4 = s4 * __expf(m4 - nm) + so * __expf(mo - nm);
                        m4 = nm;
                    }
                    if (lr == 0) {
                        smm[wr][wc][mi * 16 + rr + v] = m4;
                        sms[wr][wc][mi * 16 + rr + v] = s4;
                    }
                }
#pragma unroll
                for (int ni = 0; ni < 4; ++ni) acc[mi][ni] = (f32x4){0.f, 0.f, 0.f, 0.f};
            }
            asm volatile("s_waitcnt lgkmcnt(0)");
            SBAR();
            if (tid < 256) {
                int rl = tid & 127, wrh = tid >> 7;
                float m = smm[wrh][0][rl], s = sms[wrh][0][rl];
#pragma unroll
                for (int w = 1; w < 4; ++w) {
                    float mo = smm[wrh][w][rl], so = sms[wrh][w][rl];
                    float nm = fmaxf(m, mo);
                    s = s * __expf(m - nm) + so * __expf(mo - nm);
                    m = nm;
                }
                float nm = fmaxf(Mrun, m);
                Srun = Srun * __expf(Mrun - nm) + s * __expf(m - nm);
                Mrun = nm;
            }
            SBAR();
        }
    }
#undef MFMAQ

    if (tid < 256) {
        int rl = tid & 127, wrh = tid >> 7;
        size_t idx = (size_t)(row0 + wrh * 128 + rl) * NSPLIT + split;
        pm[idx] = Mrun;
        ps[idx] = Srun;
    }
}

// ---------------- diagonal: diag[i] = dot(emb_i, labels_i) ----------------
__global__ __launch_bounds__(256) void k_diag(const __bf16* __restrict__ E,
                                              const __bf16* __restrict__ L,
                                              float* __restrict__ diag) {
    int wave = threadIdx.x >> 6, lane = threadIdx.x & 63;
    int row = blockIdx.x * 4 + wave;
    const __bf16* e = E + (size_t)row * DPOS;
    const __bf16* l = L + (size_t)row * DPOS;
    float s = 0.f;
    for (int k = lane * 8; k < DPOS; k += 64 * 8) {
        bf16x8 a = *(const bf16x8*)(e + k);
        bf16x8 b = *(const bf16x8*)(l + k);
#pragma unroll
        for (int j = 0; j < 8; ++j) s += (float)a[j] * (float)b[j];
    }
#pragma unroll
    for (int m = 32; m >= 1; m >>= 1) s += __shfl_xor(s, m);
    if (lane == 0) diag[row] = s;
}

// ---------------- combine partials + masked mean ----------------
__global__ __launch_bounds__(256) void k_loss(const float* __restrict__ pm,
                                              const float* __restrict__ ps,
                                              const float* __restrict__ diag,
                                              const int* __restrict__ idx,
                                              float* __restrict__ out) {
    float accn = 0.f, accd = 0.f;
    for (int i = threadIdx.x; i < ROWS; i += 256) {
        float m = pm[i * NSPLIT + 0], s = ps[i * NSPLIT + 0];
#pragma unroll
        for (int c = 1; c < NSPLIT; ++c) {
            float mo = pm[i * NSPLIT + c], so = ps[i * NSPLIT + c];
            float nm = fmaxf(m, mo);
            s = s * __expf(m - nm) + so * __expf(mo - nm);
            m = nm;
        }
        float lse = m + logf(s);
        bool valid = (idx[i] != -100);
        if (valid) {
            accn += diag[i] - lse;
            accd += 1.f;
        }
    }
#pragma unroll
    for (int m = 32; m >= 1; m >>= 1) {
        accn += __shfl_xor(accn, m);
        accd += __shfl_xor(accd, m);
    }
    __shared__ float an[4], ad[4];
    int wave = threadIdx.x >> 6, lane = threadIdx.x & 63;
    if (lane == 0) { an[wave] = accn; ad[wave] = accd; }
    __syncthreads();
    if (threadIdx.x == 0) {
        float n = an[0] + an[1] + an[2] + an[3];
        float d = ad[0] + ad[1] + ad[2] + ad[3];
        out[0] = -n / d;
    }
}

extern "C" void kernel_launch(void* const* d_in, const int* in_sizes, int n_in,
                              void* d_out, int out_size, void* d_ws, size_t ws_size,
                              hipStream_t stream) {
    const float* x      = (const float*)d_in[0];   // [8192][768]
    const float* labels = (const float*)d_in[1];   // [8192][768]
    const int*   lidx   = (const int*)d_in[2];     // [8192]
    const float* vm     = (const float*)d_in[3];   // [8192]
    const float* W1     = (const float*)d_in[4];   // [768][768]
    const float* b1     = (const float*)d_in[5];
    const float* ln_g   = (const float*)d_in[6];
    const float* ln_b   = (const float*)d_in[7];
    const float* Wd     = (const float*)d_in[8];
    const float* b_dec  = (const float*)d_in[9];
    float* out = (float*)d_out;

    const size_t NE = (size_t)ROWS * DPOS;       // 6291456
    const size_t NW = (size_t)DPOS * DPOS;       // 589824
    char* p = (char*)d_ws;
    __bf16* xb   = (__bf16*)p;            p += NE * 2;
    __bf16* labb = (__bf16*)p;            p += NE * 2;
    __bf16* W1b  = (__bf16*)p;            p += NW * 2;
    __bf16* Wdb  = (__bf16*)p;            p += NW * 2;
    __bf16* hb   = (__bf16*)p;            p += NE * 2;
    __bf16* hlnb = (__bf16*)p;            p += NE * 2;
    __bf16* embb = (__bf16*)p;            p += NE * 2;
    float*  pm   = (float*)p;             p += (size_t)ROWS * NSPLIT * 4;
    float*  ps   = (float*)p;             p += (size_t)ROWS * NSPLIT * 4;
    float*  diag = (float*)p;             p += (size_t)ROWS * 4;

    hipFuncSetAttribute((const void*)k_lse8, hipFuncAttributeMaxDynamicSharedMemorySize,
                        131072);

    // convert fp32 -> bf16 (x+labels in one launch, W1+Wd in another)
    k_f2bf2<<<(2 * NE / 4) / 256, 256, 0, stream>>>(x, labels, xb, labb, (int)NE);
    k_f2bf2<<<(2 * NW / 4) / 256, 256, 0, stream>>>(W1, Wd, W1b, Wdb, (int)NW);

    // MFM block
    dim3 g1(ROWS / 128, DPOS / 64);
    k_gemm_bt<0><<<g1, 256, 0, stream>>>(xb, W1b, b1, hb);
    k_ln<<<ROWS, 256, 0, stream>>>(hb, ln_g, ln_b, hlnb);
    k_gemm_bt<1><<<g1, 256, 0, stream>>>(hlnb, Wdb, b_dec, embb);

    // contrastive loss (1-D grid, XCD-aligned split mapping)
    k_lse8<<<ROWS / BM * NSPLIT, 512, 131072, stream>>>(embb, labb, vm, pm, ps);
    k_diag<<<ROWS / 4, 256, 0, stream>>>(embb, labb, diag);
    k_loss<<<1, 256, 0, stream>>>(pm, ps, diag, lidx, out);
}

// Round 6
// 289.079 us; speedup vs baseline: 1.7919x; 1.0076x over previous
//
#include <hip/hip_runtime.h>
#include <hip/hip_bf16.h>
#include <math.h>

#define DPOS 768
#define ROWS 8192           // 32*256
#define NEG_INF_V (-10000.0f)
#define NSPLIT 8

// ---- 8-phase 256^2 geometry for k_lse8 ----
#define BM 256
#define BN 256
#define BK 64
#define CPS (ROWS / NSPLIT)   // cols per split = 1024
#define NCT (CPS / BN)        // col-tiles per block = 4
#define NKT (DPOS / BK)       // K-tiles per col-tile = 12
#define GTOT (NCT * NKT)      // 48
#define TITER (GTOT / 2)      // 24 iterations (2 K-tiles each)

typedef __attribute__((ext_vector_type(8))) __bf16 bf16x8;
typedef __attribute__((ext_vector_type(4))) __bf16 bf16x4;
typedef __attribute__((ext_vector_type(4))) float f32x4;

typedef const __attribute__((address_space(1))) unsigned int* gptr_t;
typedef __attribute__((address_space(3))) unsigned int* lptr_t;

#define SBAR() __builtin_amdgcn_s_barrier()
#define VMW(N) asm volatile("s_waitcnt vmcnt(" #N ")" ::: "memory")

// ---------------- fp32 -> bf16 conversion (two arrays per launch) ----------------
__global__ __launch_bounds__(256) void k_f2bf2(const float* __restrict__ a,
                                               const float* __restrict__ b,
                                               __bf16* __restrict__ da,
                                               __bf16* __restrict__ db, int n) {
    int i = (blockIdx.x * blockDim.x + threadIdx.x) * 4;
    const float* s = (i < n) ? a : b;
    __bf16* d = (i < n) ? da : db;
    int j = (i < n) ? i : i - n;
    float4 v = *(const float4*)(s + j);
    bf16x4 o = {(__bf16)v.x, (__bf16)v.y, (__bf16)v.z, (__bf16)v.w};
    *(bf16x4*)(d + j) = o;
}

// ---------------- GEMM C = A * B^T  (+bias, epilogue), bf16 out ----------------
// MODE 0: out = gelu(acc + bias)   MODE 1: out = acc + bias
template <int MODE>
__global__ __launch_bounds__(256) void k_gemm_bt(const __bf16* __restrict__ A,
                                                 const __bf16* __restrict__ B,
                                                 const float* __restrict__ bias,
                                                 __bf16* __restrict__ outB) {
    const int lane = threadIdx.x & 63;
    const int wave = threadIdx.x >> 6;
    const int wr = wave >> 1, wc = wave & 1;  // 2x2 waves -> 128x64 block tile
    const int row0 = blockIdx.x * 128 + wr * 64;
    const int col0 = blockIdx.y * 64 + wc * 32;
    const int lr = lane & 15;
    const int lk = (lane >> 4) * 8;

    f32x4 acc[4][2] = {};
    for (int k0 = 0; k0 < DPOS; k0 += 32) {
        bf16x8 a[4], b[2];
#pragma unroll
        for (int f = 0; f < 4; ++f)
            a[f] = *(const bf16x8*)(A + (size_t)(row0 + f * 16 + lr) * DPOS + k0 + lk);
#pragma unroll
        for (int f = 0; f < 2; ++f)
            b[f] = *(const bf16x8*)(B + (size_t)(col0 + f * 16 + lr) * DPOS + k0 + lk);
#pragma unroll
        for (int i = 0; i < 4; ++i)
#pragma unroll
            for (int j = 0; j < 2; ++j)
                acc[i][j] = __builtin_amdgcn_mfma_f32_16x16x32_bf16(a[i], b[j], acc[i][j], 0, 0, 0);
    }
    const int rr = (lane >> 4) * 4;
#pragma unroll
    for (int i = 0; i < 4; ++i)
#pragma unroll
        for (int j = 0; j < 2; ++j) {
            int col = col0 + j * 16 + lr;
            float bv = bias[col];
#pragma unroll
            for (int v = 0; v < 4; ++v) {
                int row = row0 + i * 16 + rr + v;
                float val = acc[i][j][v] + bv;
                if (MODE == 0)
                    val = 0.5f * val * (1.0f + erff(val * 0.70710678118654752f));
                outB[(size_t)row * DPOS + col] = (__bf16)val;
            }
        }
}

// ---------------- LayerNorm over last dim (768), one block per row, bf16 in/out ----------------
__global__ __launch_bounds__(256) void k_ln(const __bf16* __restrict__ h,
                                            const float* __restrict__ g,
                                            const float* __restrict__ bta,
                                            __bf16* __restrict__ out) {
    int row = blockIdx.x;
    const __bf16* hr = h + (size_t)row * DPOS;
    float v[3], s = 0.f, sq = 0.f;
#pragma unroll
    for (int t = 0; t < 3; ++t) {
        v[t] = (float)hr[threadIdx.x + t * 256];
        s += v[t];
        sq += v[t] * v[t];
    }
#pragma unroll
    for (int m = 32; m >= 1; m >>= 1) {
        s += __shfl_xor(s, m);
        sq += __shfl_xor(sq, m);
    }
    __shared__ float ss[4], sqq[4];
    int wave = threadIdx.x >> 6, lane = threadIdx.x & 63;
    if (lane == 0) { ss[wave] = s; sqq[wave] = sq; }
    __syncthreads();
    s = ss[0] + ss[1] + ss[2] + ss[3];
    sq = sqq[0] + sqq[1] + sqq[2] + sqq[3];
    float mu = s * (1.0f / DPOS);
    float var = sq * (1.0f / DPOS) - mu * mu;
    float r = rsqrtf(var + 1e-12f);
#pragma unroll
    for (int t = 0; t < 3; ++t) {
        int c = threadIdx.x + t * 256;
        out[(size_t)row * DPOS + c] = (__bf16)((v[t] - mu) * r * g[c] + bta[c]);
    }
}

// ---------------- fused logits + row-wise logsumexp, 8-phase 256^2 schedule ----------------
// R6: all ds_read addresses precomputed as lane-constant bases + compile-time
// immediates (the swizzle term (r&7)<<4 == (lr&7)<<4 is lane-constant, so every
// read offset is base + const <= 14336 -> ds_read offset immediate). Stage
// addressing uses incremental byte counters (no runtime div/mod).
__global__ __launch_bounds__(512, 1) void k_lse8(const __bf16* __restrict__ E,
                                                 const __bf16* __restrict__ L,
                                                 const float* __restrict__ vm,
                                                 float* __restrict__ pm,
                                                 float* __restrict__ ps) {
    extern __shared__ char lds[];
    __shared__ float smm[2][4][128], sms[2][4][128];
    __shared__ float svm[CPS];

    const int tid = threadIdx.x;
    const int lane = tid & 63;
    const int wave = tid >> 6;
    const int wr = wave >> 2, wc = wave & 3;
    const int lr = lane & 15;
    const int lk = (lane >> 4) * 8;
    const int rr = (lane >> 4) * 4;
    const int bid = blockIdx.x;
    const int split = bid & 7;
    const int row0 = (bid >> 3) * BM;

    // column-mask values for this split -> LDS
    svm[tid] = vm[split * CPS + tid];
    svm[tid + 512] = vm[split * CPS + tid + 512];

    // ---- row-mask bits: 32 rows per lane ----
    unsigned mrow = 0;
#pragma unroll
    for (int mi = 0; mi < 8; ++mi) {
        float4 mv = *(const float4*)(vm + row0 + wr * 128 + mi * 16 + rr);
        if (mv.x != 0.f) mrow |= 1u << (mi * 4 + 0);
        if (mv.y != 0.f) mrow |= 1u << (mi * 4 + 1);
        if (mv.z != 0.f) mrow |= 1u << (mi * 4 + 2);
        if (mv.w != 0.f) mrow |= 1u << (mi * 4 + 3);
    }

    // ---- staging geometry ----
    const int o0 = tid * 16, o1 = o0 + 8192;
    const int r0s = o0 >> 7, r1s = o1 >> 7;
    const int c0s = (o0 & 127) ^ ((r0s & 7) << 4);
    const int c1s = (o1 & 127) ^ ((r1s & 7) << 4);

    // per-thread global source bases (add kb [+ crb for B] per call)
    const char* EbA0 = (const char*)E + ((size_t)row0 + r0s) * (DPOS * 2) + c0s;
    const char* EbA1 = (const char*)E + ((size_t)row0 + r1s) * (DPOS * 2) + c1s;
    const char* LbB0 = (const char*)L + ((size_t)split * CPS + r0s) * (DPOS * 2) + c0s;
    const char* LbB1 = (const char*)L + ((size_t)split * CPS + r1s) * (DPOS * 2) + c1s;
#define HALF_GSTRIDE (128 * DPOS * 2)

    auto stageA = [&](int slot, int half, int kb) {
        char* dst = lds + slot * 65536 + half * 16384;
        __builtin_amdgcn_global_load_lds((gptr_t)(EbA0 + (size_t)half * HALF_GSTRIDE + kb),
                                         (lptr_t)(dst + o0), 16, 0, 0);
        __builtin_amdgcn_global_load_lds((gptr_t)(EbA1 + (size_t)half * HALF_GSTRIDE + kb),
                                         (lptr_t)(dst + o1), 16, 0, 0);
    };
    auto stageB = [&](int slot, int half, int kb, int crb) {
        char* dst = lds + slot * 65536 + 32768 + half * 16384;
        __builtin_amdgcn_global_load_lds((gptr_t)(LbB0 + (size_t)half * HALF_GSTRIDE + crb + kb),
                                         (lptr_t)(dst + o0), 16, 0, 0);
        __builtin_amdgcn_global_load_lds((gptr_t)(LbB1 + (size_t)half * HALF_GSTRIDE + crb + kb),
                                         (lptr_t)(dst + o1), 16, 0, 0);
    };

    // ---- precomputed ds_read base offsets (lane-constant) ----
    const int sws = (lr & 7) << 4;
    const int colK0 = (lk * 2) ^ sws;
    const int colK1 = ((32 + lk) * 2) ^ sws;
    const int aRow = (wr * 128 + lr) * 128;
    const int bRow = (wc * 64 + lr) * 128 + 32768;
    const int offA0k0 = aRow + colK0,           offA0k1 = aRow + colK1;
    const int offA1k0 = 65536 + aRow + colK0,   offA1k1 = 65536 + aRow + colK1;
    const int offB0k0 = bRow + colK0,           offB0k1 = bRow + colK1;
    const int offB1k0 = 65536 + bRow + colK0,   offB1k1 = 65536 + bRow + colK1;

    bf16x8 a[4][2], bLo[2][2], bHi[2][2];
    f32x4 acc[8][4];
#pragma unroll
    for (int mi = 0; mi < 8; ++mi)
#pragma unroll
        for (int ni = 0; ni < 4; ++ni) acc[mi][ni] = (f32x4){0.f, 0.f, 0.f, 0.f};

    // reads: base + compile-time immediate (mh*8192 + mi*2048 <= 14336)
    auto readA = [&](int baseK0, int baseK1, int mh) {
#pragma unroll
        for (int mi = 0; mi < 4; ++mi) {
            a[mi][0] = *(const bf16x8*)(lds + baseK0 + mh * 8192 + mi * 2048);
            a[mi][1] = *(const bf16x8*)(lds + baseK1 + mh * 8192 + mi * 2048);
        }
    };
    auto readB = [&](int baseK0, int baseK1, int nh, bf16x8 (&dst)[2][2]) {
#pragma unroll
        for (int ni = 0; ni < 2; ++ni) {
            dst[ni][0] = *(const bf16x8*)(lds + baseK0 + nh * 4096 + ni * 2048);
            dst[ni][1] = *(const bf16x8*)(lds + baseK1 + nh * 4096 + ni * 2048);
        }
    };

#define MFMAQ(MI0, NI0, B) do { \
    __builtin_amdgcn_s_setprio(1); \
    _Pragma("unroll") \
    for (int mi = 0; mi < 4; ++mi) \
        _Pragma("unroll") \
        for (int ni = 0; ni < 2; ++ni) \
            _Pragma("unroll") \
            for (int kk = 0; kk < 2; ++kk) \
                acc[MI0 + mi][NI0 + ni] = __builtin_amdgcn_mfma_f32_16x16x32_bf16( \
                    a[mi][kk], B[ni][kk], acc[MI0 + mi][NI0 + ni], 0, 0, 0); \
    __builtin_amdgcn_s_setprio(0); \
} while (0)

    float Mrun = -1e30f, Srun = 0.f;

    // ---- prologue: s0 A+B (g=0), s1 B (g=1), s1 A-lo (g=1) = 14 loads ----
    stageA(0, 0, 0); stageA(0, 1, 0); stageB(0, 0, 0, 0); stageB(0, 1, 0, 0);
    stageB(1, 0, 128, 0); stageB(1, 1, 128, 0); stageA(1, 0, 128);
    asm volatile("s_waitcnt lgkmcnt(0)");
    VMW(6);
    SBAR();

    // incremental stage counters: kb = (g%NKT)*128 bytes, crb = (g/NKT)*BN*rowstride
    // for g1(=2i+1), gA(=2i+2), gB(=2i+3)
    int kb1 = 128, crb1 = 0;        // g=1
    int kbA = 256, crbA = 0;        // g=2
    int kbB = 384, crbB = 0;        // g=3
#define KWRAP (NKT * 128)           // 1536
#define CADV (BN * DPOS * 2)        // 393216

#pragma unroll 1
    for (int i = 0; i < TITER; ++i) {
        const bool nt = (i + 1 < TITER);

        // ph1: read s0 A-mh0 + B-nh0; stage s1A-hi (g1)
        readA(offA0k0, offA0k1, 0); readB(offB0k0, offB0k1, 0, bLo);
        stageA(1, 1, kb1);
        SBAR(); MFMAQ(0, 0, bLo); SBAR();
        // ph2: read s0 B-nh1
        readB(offB0k0, offB0k1, 1, bHi);
        SBAR(); MFMAQ(0, 2, bHi); SBAR();
        // ph3: read s0 A-mh1; stage s0B-lo (g0+2)
        readA(offA0k0, offA0k1, 1);
        if (nt) stageB(0, 0, kbA, crbA);
        SBAR(); MFMAQ(4, 0, bLo); SBAR();
        // ph4: stage s0B-hi + s0A-lo (g0+2); counted wait releases s1
        if (nt) { stageB(0, 1, kbA, crbA); stageA(0, 0, kbA); VMW(6); }
        else { VMW(0); }
        SBAR(); MFMAQ(4, 2, bHi); SBAR();
        // ph5: read s1 A-mh0 + B-nh0; stage s0A-hi (g0+2)
        readA(offA1k0, offA1k1, 0); readB(offB1k0, offB1k1, 0, bLo);
        if (nt) stageA(0, 1, kbA);
        SBAR(); MFMAQ(0, 0, bLo); SBAR();
        // ph6: read s1 B-nh1
        readB(offB1k0, offB1k1, 1, bHi);
        SBAR(); MFMAQ(0, 2, bHi); SBAR();
        // ph7: read s1 A-mh1; stage s1B-lo (g1+2)
        readA(offA1k0, offA1k1, 1);
        if (nt) stageB(1, 0, kbB, crbB);
        SBAR(); MFMAQ(4, 0, bLo); SBAR();
        // ph8: stage s1B-hi + s1A-lo (g1+2); counted wait releases s0
        if (nt) { stageB(1, 1, kbB, crbB); stageA(1, 0, kbB); VMW(6); }
        SBAR(); MFMAQ(4, 2, bHi); SBAR();

        // advance stage counters by 2 K-tiles each
        kb1 += 256; if (kb1 >= KWRAP) { kb1 -= KWRAP; crb1 += CADV; }
        kbA += 256; if (kbA >= KWRAP) { kbA -= KWRAP; crbA += CADV; }
        kbB += 256; if (kbB >= KWRAP) { kbB -= KWRAP; crbB += CADV; }

        // ---- col-tile epilogue: fused online-softmax over this 256x256 logits tile ----
        if ((i % (NKT / 2)) == (NKT / 2 - 1)) {
            const int ct = i / (NKT / 2);
            float cmv[4];
#pragma unroll
            for (int ni = 0; ni < 4; ++ni)
                cmv[ni] = svm[ct * BN + wc * 64 + ni * 16 + lr];
#pragma unroll
            for (int mi = 0; mi < 8; ++mi) {
#pragma unroll
                for (int v = 0; v < 4; ++v) {
                    bool rv = (mrow >> (mi * 4 + v)) & 1u;
                    float x0 = acc[mi][0][v] + ((rv && cmv[0] == 0.f) ? NEG_INF_V : 0.f);
                    float x1 = acc[mi][1][v] + ((rv && cmv[1] == 0.f) ? NEG_INF_V : 0.f);
                    float x2 = acc[mi][2][v] + ((rv && cmv[2] == 0.f) ? NEG_INF_V : 0.f);
                    float x3 = acc[mi][3][v] + ((rv && cmv[3] == 0.f) ? NEG_INF_V : 0.f);
                    float m4 = fmaxf(fmaxf(x0, x1), fmaxf(x2, x3));
                    float s4 = __expf(x0 - m4) + __expf(x1 - m4) +
                               __expf(x2 - m4) + __expf(x3 - m4);
#pragma unroll
                    for (int d = 1; d < 16; d <<= 1) {
                        float mo = __shfl_xor(m4, d);
                        float so = __shfl_xor(s4, d);
                        float nm = fmaxf(m4, mo);
                        s4 = s4 * __expf(m4 - nm) + so * __expf(mo - nm);
                        m4 = nm;
                    }
                    if (lr == 0) {
                        smm[wr][wc][mi * 16 + rr + v] = m4;
                        sms[wr][wc][mi * 16 + rr + v] = s4;
                    }
                }
#pragma unroll
                for (int ni = 0; ni < 4; ++ni) acc[mi][ni] = (f32x4){0.f, 0.f, 0.f, 0.f};
            }
            asm volatile("s_waitcnt lgkmcnt(0)");
            SBAR();
            if (tid < 256) {
                int rl = tid & 127, wrh = tid >> 7;
                float m = smm[wrh][0][rl], s = sms[wrh][0][rl];
#pragma unroll
                for (int w = 1; w < 4; ++w) {
                    float mo = smm[wrh][w][rl], so = sms[wrh][w][rl];
                    float nm = fmaxf(m, mo);
                    s = s * __expf(m - nm) + so * __expf(mo - nm);
                    m = nm;
                }
                float nm = fmaxf(Mrun, m);
                Srun = Srun * __expf(Mrun - nm) + s * __expf(m - nm);
                Mrun = nm;
            }
            SBAR();
        }
    }
#undef MFMAQ

    if (tid < 256) {
        int rl = tid & 127, wrh = tid >> 7;
        size_t idx = (size_t)(row0 + wrh * 128 + rl) * NSPLIT + split;
        pm[idx] = Mrun;
        ps[idx] = Srun;
    }
}

// ---------------- diagonal: diag[i] = dot(emb_i, labels_i) ----------------
__global__ __launch_bounds__(256) void k_diag(const __bf16* __restrict__ E,
                                              const __bf16* __restrict__ L,
                                              float* __restrict__ diag) {
    int wave = threadIdx.x >> 6, lane = threadIdx.x & 63;
    int row = blockIdx.x * 4 + wave;
    const __bf16* e = E + (size_t)row * DPOS;
    const __bf16* l = L + (size_t)row * DPOS;
    float s = 0.f;
    for (int k = lane * 8; k < DPOS; k += 64 * 8) {
        bf16x8 a = *(const bf16x8*)(e + k);
        bf16x8 b = *(const bf16x8*)(l + k);
#pragma unroll
        for (int j = 0; j < 8; ++j) s += (float)a[j] * (float)b[j];
    }
#pragma unroll
    for (int m = 32; m >= 1; m >>= 1) s += __shfl_xor(s, m);
    if (lane == 0) diag[row] = s;
}

// ---------------- combine partials + masked mean ----------------
__global__ __launch_bounds__(256) void k_loss(const float* __restrict__ pm,
                                              const float* __restrict__ ps,
                                              const float* __restrict__ diag,
                                              const int* __restrict__ idx,
                                              float* __restrict__ out) {
    float accn = 0.f, accd = 0.f;
    for (int i = threadIdx.x; i < ROWS; i += 256) {
        float m = pm[i * NSPLIT + 0], s = ps[i * NSPLIT + 0];
#pragma unroll
        for (int c = 1; c < NSPLIT; ++c) {
            float mo = pm[i * NSPLIT + c], so = ps[i * NSPLIT + c];
            float nm = fmaxf(m, mo);
            s = s * __expf(m - nm) + so * __expf(mo - nm);
            m = nm;
        }
        float lse = m + logf(s);
        bool valid = (idx[i] != -100);
        if (valid) {
            accn += diag[i] - lse;
            accd += 1.f;
        }
    }
#pragma unroll
    for (int m = 32; m >= 1; m >>= 1) {
        accn += __shfl_xor(accn, m);
        accd += __shfl_xor(accd, m);
    }
    __shared__ float an[4], ad[4];
    int wave = threadIdx.x >> 6, lane = threadIdx.x & 63;
    if (lane == 0) { an[wave] = accn; ad[wave] = accd; }
    __syncthreads();
    if (threadIdx.x == 0) {
        float n = an[0] + an[1] + an[2] + an[3];
        float d = ad[0] + ad[1] + ad[2] + ad[3];
        out[0] = -n / d;
    }
}

extern "C" void kernel_launch(void* const* d_in, const int* in_sizes, int n_in,
                              void* d_out, int out_size, void* d_ws, size_t ws_size,
                              hipStream_t stream) {
    const float* x      = (const float*)d_in[0];   // [8192][768]
    const float* labels = (const float*)d_in[1];   // [8192][768]
    const int*   lidx   = (const int*)d_in[2];     // [8192]
    const float* vm     = (const float*)d_in[3];   // [8192]
    const float* W1     = (const float*)d_in[4];   // [768][768]
    const float* b1     = (const float*)d_in[5];
    const float* ln_g   = (const float*)d_in[6];
    const float* ln_b   = (const float*)d_in[7];
    const float* Wd     = (const float*)d_in[8];
    const float* b_dec  = (const float*)d_in[9];
    float* out = (float*)d_out;

    const size_t NE = (size_t)ROWS * DPOS;       // 6291456
    const size_t NW = (size_t)DPOS * DPOS;       // 589824
    char* p = (char*)d_ws;
    __bf16* xb   = (__bf16*)p;            p += NE * 2;
    __bf16* labb = (__bf16*)p;            p += NE * 2;
    __bf16* W1b  = (__bf16*)p;            p += NW * 2;
    __bf16* Wdb  = (__bf16*)p;            p += NW * 2;
    __bf16* hb   = (__bf16*)p;            p += NE * 2;
    __bf16* hlnb = (__bf16*)p;            p += NE * 2;
    __bf16* embb = (__bf16*)p;            p += NE * 2;
    float*  pm   = (float*)p;             p += (size_t)ROWS * NSPLIT * 4;
    float*  ps   = (float*)p;             p += (size_t)ROWS * NSPLIT * 4;
    float*  diag = (float*)p;             p += (size_t)ROWS * 4;

    hipFuncSetAttribute((const void*)k_lse8, hipFuncAttributeMaxDynamicSharedMemorySize,
                        131072);

    // convert fp32 -> bf16 (x+labels in one launch, W1+Wd in another)
    k_f2bf2<<<(2 * NE / 4) / 256, 256, 0, stream>>>(x, labels, xb, labb, (int)NE);
    k_f2bf2<<<(2 * NW / 4) / 256, 256, 0, stream>>>(W1, Wd, W1b, Wdb, (int)NW);

    // MFM block
    dim3 g1(ROWS / 128, DPOS / 64);
    k_gemm_bt<0><<<g1, 256, 0, stream>>>(xb, W1b, b1, hb);
    k_ln<<<ROWS, 256, 0, stream>>>(hb, ln_g, ln_b, hlnb);
    k_gemm_bt<1><<<g1, 256, 0, stream>>>(hlnb, Wdb, b_dec, embb);

    // contrastive loss (1-D grid, XCD-aligned split mapping)
    k_lse8<<<ROWS / BM * NSPLIT, 512, 131072, stream>>>(embb, labb, vm, pm, ps);
    k_diag<<<ROWS / 4, 256, 0, stream>>>(embb, labb, diag);
    k_loss<<<1, 256, 0, stream>>>(pm, ps, diag, lidx, out);
}